// Round 8
// baseline (1084.157 us; speedup 1.0000x reference)
//
#include <hip/hip_runtime.h>
#include <hip/hip_bf16.h>
#include <math.h>

#define D_MODEL 1024
#define D_INNER 2048
#define D_STATE 16
#define DT_RANK 64
#define BB 4
#define LL 4096
#define NROWS (BB * LL)   // 16384
#define NCHUNK 32
#define TCHUNK 128        // NCHUNK * TCHUNK == LL

typedef __hip_bfloat16 bf16;
typedef __attribute__((ext_vector_type(8))) short short8;   // MFMA A/B frag (8 bf16)
typedef __attribute__((ext_vector_type(4))) float floatx4;  // MFMA C/D frag

__device__ __forceinline__ float silu_f(float x) { return x / (1.f + __expf(-x)); }
__device__ __forceinline__ float softplus_f(float x) { return x > 20.f ? x : log1pf(__expf(x)); }
__device__ __forceinline__ float bf2f(bf16 v) { return __bfloat162float(v); }
__device__ __forceinline__ bf16 f2bf(float v) { return __float2bfloat16(v); }

// raw v_exp_f32 (2^x). Callers pre-fold the log2e factor into the operand.
__device__ __forceinline__ float exp2_raw(float x) {
    float r;
    asm("v_exp_f32 %0, %1" : "=v"(r) : "v"(x));
    return r;
}

// async 16B global -> LDS copy (gfx950 global_load_lds_dwordx4).
// HW semantics: LDS dest = wave-uniform base + lane*16 [m97/m104].
__device__ __forceinline__ void gl2lds16(const bf16* g, short* lds) {
    __builtin_amdgcn_global_load_lds(
        (const __attribute__((address_space(1))) void*)g,
        (__attribute__((address_space(3))) void*)lds, 16, 0, 0);
}

// decode 8 consecutive bf16 (16-byte aligned) to fp32
__device__ __forceinline__ void load8_bf16(const bf16* p, float* f) {
    uint4 raw = *(const uint4*)p;
    unsigned int w0 = raw.x, w1 = raw.y, w2 = raw.z, w3 = raw.w;
    f[0] = __uint_as_float((w0 & 0xffffu) << 16);
    f[1] = __uint_as_float(w0 & 0xffff0000u);
    f[2] = __uint_as_float((w1 & 0xffffu) << 16);
    f[3] = __uint_as_float(w1 & 0xffff0000u);
    f[4] = __uint_as_float((w2 & 0xffffu) << 16);
    f[5] = __uint_as_float(w2 & 0xffff0000u);
    f[6] = __uint_as_float((w3 & 0xffffu) << 16);
    f[7] = __uint_as_float(w3 & 0xffff0000u);
}

// ---------------------------------------------------------------------------
// Input dtype detection (1 = fp32 inputs, 0 = bf16 inputs).
// ---------------------------------------------------------------------------
__global__ void detect_dtype(const void* xsrc, int* flag) {
    const unsigned short* p = (const unsigned short*)xsrc;
    int tid = threadIdx.x;
    int bad = 0;
    for (int i = tid; i < 2048; i += 256) {
        float v = __uint_as_float(((unsigned int)p[i]) << 16);
        if (!isfinite(v) || fabsf(v) > 1e6f) bad = 1;
    }
    __shared__ int sbad;
    if (tid == 0) sbad = 0;
    __syncthreads();
    if (bad) atomicOr(&sbad, 1);
    __syncthreads();
    if (tid == 0) *flag = sbad;
}

__global__ __launch_bounds__(256) void convert_to_bf16(
    const void* __restrict__ src, bf16* __restrict__ dst, int n,
    const int* __restrict__ flag)
{
    int i = blockIdx.x * 256 + threadIdx.x;
    if (i >= n) return;
    if (*flag)
        dst[i] = f2bf(((const float*)src)[i]);
    else
        dst[i] = ((const bf16*)src)[i];
}

// batch of small conversions in a single dispatch (saves ~7 launches)
struct CvtBatch {
    const void* src[8];
    bf16* dst[8];
    int n[8];
    int blockStart[9];   // prefix of ceil(n/256)
    int count;
};
__global__ __launch_bounds__(256) void convert_batch(CvtBatch b, const int* __restrict__ flag) {
    int bi = blockIdx.x;
    int seg = 0;
    while (seg + 1 < b.count && bi >= b.blockStart[seg + 1]) seg++;
    int i = (bi - b.blockStart[seg]) * 256 + threadIdx.x;
    if (i >= b.n[seg]) return;
    if (*flag)
        b.dst[seg][i] = f2bf(((const float*)b.src[seg])[i]);
    else
        b.dst[seg][i] = ((const bf16*)b.src[seg])[i];
}

// combine 4 split-K fp32 partials -> bf16
__global__ __launch_bounds__(256) void combine_splitk(
    const float* __restrict__ p, bf16* __restrict__ out, int n, int stride)
{
    int i = blockIdx.x * 256 + threadIdx.x;
    if (i >= n) return;
    float v = (p[i] + p[i + (size_t)stride]) +
              (p[i + 2 * (size_t)stride] + p[i + 3 * (size_t)stride]);
    out[i] = f2bf(v);
}

// ---------------------------------------------------------------------------
// Legacy 128x128 async-staged MFMA GEMM (m97 structure).
// EPI: 0 plain, 1 softplus+bias, 2 split store, 3 split-K fp32 partials
// (R7: x_proj was 128 blocks = half-chip-idle with a 64-deep serial K chain;
//  EPI=3 uses blockIdx.x as the K-slice: grid (KS, M/128), each block does
//  K columns starting at slice*K, storing fp32 partials to
//  (float*)C + (slice*Mrows + row)*ldc + col.  Mrows passed via Nsplit.)
// ---------------------------------------------------------------------------
template <int EPI>
__global__ __launch_bounds__(256) void gemm_async(
    const bf16* __restrict__ A, int lda,
    const bf16* __restrict__ W, int ldw, int K,
    const bf16* __restrict__ bias,
    bf16* __restrict__ C, bf16* __restrict__ C2, int ldc,
    int N, int Nsplit)
{
    __shared__ short As[128 * 32];   // [m][k], 8 KB
    __shared__ short Bs[128 * 32];   // [n][k], 8 KB

    const int tid = threadIdx.x;
    const int m0 = blockIdx.y * 128;
    const int n0 = (EPI == 3) ? 0 : blockIdx.x * 128;
    const int ks = (EPI == 3) ? (int)blockIdx.x * K : 0;   // K-slice offset
    const int wid = tid >> 6;
    const int lane = tid & 63;
    const int wm = wid & 1;
    const int wn = wid >> 1;
    const int lm = lane & 15;
    const int quad = lane >> 4;

    floatx4 acc[4][4];
#pragma unroll
    for (int i = 0; i < 4; i++)
#pragma unroll
        for (int j = 0; j < 4; j++) acc[i][j] = (floatx4){0.f, 0.f, 0.f, 0.f};

    for (int k0 = 0; k0 < K; k0 += 32) {
#pragma unroll
        for (int j = 0; j < 2; j++) {
            int cbase = (wid * 2 + j) * 64;       // wave-uniform
            int c = cbase + lane;
            int row = c >> 2, seg = c & 3;
            gl2lds16(A + (size_t)(m0 + row) * lda + ks + k0 + seg * 8, &As[cbase * 8]);
        }
#pragma unroll
        for (int j = 0; j < 2; j++) {
            int cbase = (wid * 2 + j) * 64;
            int c = cbase + lane;
            int row = c >> 2, seg = c & 3;
            int wrow = n0 + row; if (wrow >= N) wrow = N - 1;
            gl2lds16(W + (size_t)wrow * ldw + ks + k0 + seg * 8, &Bs[cbase * 8]);
        }
        __syncthreads();

        short8 af[4], bfr[4];
#pragma unroll
        for (int mt = 0; mt < 4; mt++)
            af[mt] = *(const short8*)&As[(wm * 64 + mt * 16 + lm) * 32 + quad * 8];
#pragma unroll
        for (int nt = 0; nt < 4; nt++)
            bfr[nt] = *(const short8*)&Bs[(wn * 64 + nt * 16 + lm) * 32 + quad * 8];
        __syncthreads();

#pragma unroll
        for (int mt = 0; mt < 4; mt++)
#pragma unroll
            for (int nt = 0; nt < 4; nt++)
                acc[mt][nt] = __builtin_amdgcn_mfma_f32_16x16x32_bf16(
                    af[mt], bfr[nt], acc[mt][nt], 0, 0, 0);
    }

#pragma unroll
    for (int mt = 0; mt < 4; mt++) {
#pragma unroll
        for (int nt = 0; nt < 4; nt++) {
            int col = n0 + wn * 64 + nt * 16 + lm;
            if (col >= N) continue;
            int rbase = m0 + wm * 64 + mt * 16 + quad * 4;
#pragma unroll
            for (int r = 0; r < 4; r++) {
                float v = acc[mt][nt][r];
                if (EPI == 3) {
                    ((float*)C)[((size_t)blockIdx.x * Nsplit + rbase + r) * ldc + col] = v;
                } else if (EPI == 1) {
                    C[(size_t)(rbase + r) * ldc + col] = f2bf(softplus_f(v + bf2f(bias[col])));
                } else if (EPI == 2) {
                    if (col < Nsplit)
                        C[(size_t)(rbase + r) * ldc + col] = f2bf(v);
                    else
                        C2[(size_t)(rbase + r) * ldc + (col - Nsplit)] = f2bf(v);
                } else {
                    C[(size_t)(rbase + r) * ldc + col] = f2bf(v);
                }
            }
        }
    }
}

// ---------------------------------------------------------------------------
// 256x256 MFMA GEMM, R2 structure: all-reads-up-front + 2 barriers/K-tile.
// C[M,N] = A[M,K] @ W[N,K]^T.  Requires M == 16384 (by-panels = 64),
// N%256==0, K%64==0, K>=64.  EPI: 0 plain, 1 softplus+bias, 2 split.
// R7: by-fastest XCD block mapping — each XCD owns 8 contiguous by-panels
// (its full A set, 4MB = L2) and walks bx slowly, so W panels are consumed
// by all 8 rows while resident.  Predicted FETCH 147->~105MB on in_proj.
// ---------------------------------------------------------------------------
template <int EPI>
__global__ __launch_bounds__(512, 2) void gemm256(
    const bf16* __restrict__ A, int lda,
    const bf16* __restrict__ W, int ldw, int K,
    const bf16* __restrict__ bias,
    bf16* __restrict__ C, bf16* __restrict__ C2, int ldc,
    int NBX, int Nsplit)
{
    __shared__ short lds[65536];   // 128 KB: [buf][A 16384 | B 16384] shorts

    const int tid = threadIdx.x;
    const int wid = tid >> 6;
    const int lane = tid & 63;
    const int lm = lane & 15;
    const int quad = lane >> 4;
    const int wm = wid >> 2;      // 0..1
    const int wn = wid & 3;       // 0..3

    // by-fastest XCD mapping (callers guarantee gridDim.x == NBX*64, i.e.
    // 64 by-panels, 8 per XCD).  Bijective: wg = xcd + 8*(by_l + 8*bx).
    const int wg = (int)blockIdx.x;
    const int by = (wg & 7) * 8 + ((wg >> 3) & 7);
    const int bx = wg >> 6;
    const int m0 = by * 256;
    const int n0 = bx * 256;

    const int NT = K >> 6;

    floatx4 acc[2][4][2][2];
#pragma unroll
    for (int a = 0; a < 2; a++)
#pragma unroll
        for (int b = 0; b < 4; b++)
#pragma unroll
            for (int c = 0; c < 2; c++)
#pragma unroll
                for (int d = 0; d < 2; d++) acc[a][b][c][d] = (floatx4){0.f, 0.f, 0.f, 0.f};

    // stage one 16 KB half of the A (resp. B) tile of K-step t_ into buffer bsel.
    auto stageA = [&](int bsel, int t_, int half) {
        short* base = &lds[bsel * 32768];
        const bf16* g = A + (size_t)m0 * lda + t_ * 64;
#pragma unroll
        for (int part = 0; part < 2; part++) {
            int cbase = half * 512 + part * 1024 + wid * 64;   // wave-uniform
            int c = cbase + lane;
            int row = c >> 3;
            int gs = (c & 7) ^ (row & 7);                      // inverse swizzle on source
            gl2lds16(g + (size_t)row * lda + gs * 8, base + cbase * 8);
        }
    };
    auto stageB = [&](int bsel, int t_, int half) {
        short* base = &lds[bsel * 32768 + 16384];
        const bf16* g = W + (size_t)n0 * ldw + t_ * 64;
#pragma unroll
        for (int part = 0; part < 2; part++) {
            int cbase = half * 1024 + part * 512 + wid * 64;
            int c = cbase + lane;
            int row = c >> 3;
            int gs = (c & 7) ^ (row & 7);
            gl2lds16(g + (size_t)row * ldw + gs * 8, base + cbase * 8);
        }
    };

    // ---- prologue
    stageA(0, 0, 0); stageA(0, 0, 1); stageB(0, 0, 0); stageB(0, 0, 1);
    if (NT > 1) { stageA(1, 1, 0); stageB(1, 1, 1); }
    if (NT > 1) asm volatile("s_waitcnt vmcnt(4)" ::: "memory");
    else        asm volatile("s_waitcnt vmcnt(0)" ::: "memory");
    __builtin_amdgcn_s_barrier();

#define READ_A(DST, MH)                                                         \
    _Pragma("unroll")                                                           \
    for (int mt = 0; mt < 4; mt++) {                                            \
        int r = wm * 128 + (MH) * 64 + mt * 16 + lm;                            \
        _Pragma("unroll")                                                       \
        for (int kk = 0; kk < 2; kk++)                                          \
            DST[mt][kk] = *(const short8*)&As_[r * 64 + (((kk * 4 + quad) ^ (r & 7)) * 8)]; \
    }
#define READ_B(DST, NH)                                                         \
    _Pragma("unroll")                                                           \
    for (int nf = 0; nf < 2; nf++) {                                            \
        int r = (NH) * 128 + wn * 32 + nf * 16 + lm;                            \
        _Pragma("unroll")                                                       \
        for (int kk = 0; kk < 2; kk++)                                          \
            DST[nf][kk] = *(const short8*)&Bs_[r * 64 + (((kk * 4 + quad) ^ (r & 7)) * 8)]; \
    }
#define MFMA16(AF, BV, MH, NH)                                                  \
    __builtin_amdgcn_s_setprio(1);                                              \
    _Pragma("unroll")                                                           \
    for (int mt = 0; mt < 4; mt++)                                              \
        _Pragma("unroll")                                                       \
        for (int nf = 0; nf < 2; nf++)                                          \
            _Pragma("unroll")                                                   \
            for (int kk = 0; kk < 2; kk++)                                      \
                acc[MH][mt][NH][nf] = __builtin_amdgcn_mfma_f32_16x16x32_bf16(  \
                    AF[mt][kk], BV[nf][kk], acc[MH][mt][NH][nf], 0, 0, 0);      \
    __builtin_amdgcn_s_setprio(0);

    for (int t = 0; t < NT; t++) {
        const int buf = t & 1;
        const int bufn = buf ^ 1;
        short* As_ = &lds[buf * 32768];
        short* Bs_ = &lds[buf * 32768 + 16384];
        short8 af0[4][2], af1[4][2], bv0[2][2], bv1[2][2];

        READ_A(af0, 0)
        READ_B(bv0, 0)
        READ_B(bv1, 1)
        READ_A(af1, 1)

        if (t + 1 < NT) { stageA(bufn, t + 1, 1); stageB(bufn, t + 1, 0); }

        MFMA16(af0, bv0, 0, 0)
        MFMA16(af0, bv1, 0, 1)

        __builtin_amdgcn_s_barrier();   // #1

        if (t + 2 < NT) { stageA(buf, t + 2, 0); stageB(buf, t + 2, 1); }

        MFMA16(af1, bv1, 1, 1)
        MFMA16(af1, bv0, 1, 0)

        if (t + 2 < NT)      { asm volatile("s_waitcnt vmcnt(4)" ::: "memory"); }
        else if (t + 1 < NT) { asm volatile("s_waitcnt vmcnt(0)" ::: "memory"); }
        __builtin_amdgcn_s_barrier();   // #2
    }
#undef READ_A
#undef READ_B
#undef MFMA16

    // epilogue: C/D layout col = lane&15, row = quad*4 + r  [m89/m91]
#pragma unroll
    for (int mh = 0; mh < 2; mh++)
#pragma unroll
        for (int mt = 0; mt < 4; mt++)
#pragma unroll
            for (int nh = 0; nh < 2; nh++)
#pragma unroll
                for (int nf = 0; nf < 2; nf++) {
                    int col = n0 + nh * 128 + wn * 32 + nf * 16 + lm;
                    int rbase = m0 + wm * 128 + mh * 64 + mt * 16 + quad * 4;
#pragma unroll
                    for (int r = 0; r < 4; r++) {
                        float v = acc[mh][mt][nh][nf][r];
                        if (EPI == 1) v = softplus_f(v + bf2f(bias[col]));
                        if (EPI == 2) {
                            if (col < Nsplit)
                                C[(size_t)(rbase + r) * ldc + col] = f2bf(v);
                            else
                                C2[(size_t)(rbase + r) * ldc + (col - Nsplit)] = f2bf(v);
                        } else {
                            C[(size_t)(rbase + r) * ldc + col] = f2bf(v);
                        }
                    }
                }
}

// ---------------------------------------------------------------------------
// Causal depthwise conv1d (width 4) + bias + SiLU. bf16 in/out, fp32 math.
// ---------------------------------------------------------------------------
__global__ __launch_bounds__(256) void conv_silu(
    const bf16* __restrict__ u,
    bf16* __restrict__ u_c,
    const bf16* __restrict__ w,
    const bf16* __restrict__ bias)
{
    int gid = blockIdx.x * 256 + threadIdx.x;
    if (gid >= NROWS * D_INNER) return;
    int d = gid & (D_INNER - 1);
    int row = gid >> 11;
    int l = row & (LL - 1);
    float acc = bf2f(bias[d]);
#pragma unroll
    for (int t = 0; t < 4; t++) {
        int ls = l - 3 + t;
        if (ls >= 0)
            acc = fmaf(bf2f(w[d * 4 + t]), bf2f(u[(size_t)(row - 3 + t) * D_INNER + d]), acc);
    }
    u_c[(size_t)row * D_INNER + d] = f2bf(silu_f(acc));
}

// ---------------------------------------------------------------------------
// Chunked selective scan (3 phases).  R6: A_log read in original precision
// so the POW16 structure check passes (bf16 copy failed the 1e-4 check).
// ---------------------------------------------------------------------------

// dA[0..15] = q^(n+1), 15 muls, depth ~4
#define POW16(DA, Q) do {                                                     \
    float q1 = (Q);                                                           \
    float q2 = q1 * q1;                                                       \
    float q3 = q2 * q1;                                                       \
    float q4 = q2 * q2;                                                       \
    float q8 = q4 * q4;                                                       \
    DA[0] = q1;       DA[1] = q2;       DA[2] = q3;       DA[3] = q4;         \
    DA[4] = q4 * q1;  DA[5] = q4 * q2;  DA[6] = q4 * q3;  DA[7] = q8;         \
    DA[8] = q8 * q1;  DA[9] = q8 * q2;  DA[10] = q8 * q3; DA[11] = q8 * q4;   \
    DA[12] = q8 * DA[4]; DA[13] = q8 * DA[5]; DA[14] = q8 * DA[6];            \
    DA[15] = q8 * q8;                                                         \
} while (0)

__device__ __forceinline__ bool ac_structured(const float* Ac) {
    float a0 = Ac[0];
    bool ok = true;
#pragma unroll
    for (int n = 1; n < 16; n++) {
        float want = (float)(n + 1) * a0;
        ok = ok && (fabsf(Ac[n] - want) <= 1e-4f * fabsf(want) + 1e-12f);
    }
    return ok;
}

// load A_log row d (16 values) in original precision, produce exp2-domain Ac
__device__ __forceinline__ void load_Ac(const void* A_log_raw, int fp32, int d, float* Ac) {
    float f[16];
    if (fp32) {
        const float* ap = (const float*)A_log_raw + (size_t)d * 16;
#pragma unroll
        for (int n = 0; n < 16; n++) f[n] = ap[n];
    } else {
        const bf16* ap = (const bf16*)A_log_raw + (size_t)d * 16;
        load8_bf16(ap, f);
        load8_bf16(ap + 8, f + 8);
    }
#pragma unroll
    for (int n = 0; n < 16; n++) Ac[n] = -__expf(f[n]) * 1.4426950408889634f;
}

__global__ __launch_bounds__(256) void scan_p1(
    const bf16* __restrict__ delta,
    const bf16* __restrict__ uc,
    const bf16* __restrict__ x_dbl,
    const void* __restrict__ A_log_raw,
    const int* __restrict__ flag,
    float* __restrict__ Pbuf, float* __restrict__ Sbuf)
{
    __shared__ float Bsh[TCHUNK * 16];
    const int tid = threadIdx.x;
    const int bx = blockIdx.x;
    const int dt = bx & 7;
    const int c = (bx >> 3) & (NCHUNK - 1);
    const int b = bx / (NCHUNK * 8);
    const int d = dt * 256 + tid;
    const int rowb = b * LL + c * TCHUNK;

    if (tid < TCHUNK) {
        float f[16];
        const bf16* p = x_dbl + (size_t)(rowb + tid) * 96 + DT_RANK;
        load8_bf16(p, f);
        load8_bf16(p + 8, f + 8);
#pragma unroll
        for (int n = 0; n < 16; n++) Bsh[tid * 16 + n] = f[n];
    }

    float Ac[16];   // -exp(A_log) * log2e  (exp2-domain)
    load_Ac(A_log_raw, *flag, d, Ac);
    const float a0 = Ac[0];
    const bool fast = ac_structured(Ac);
    __syncthreads();

    float h[16];
    float sdl = 0.f;   // sum of dl over chunk -> Pp via exp2(Ac*sdl)
#pragma unroll
    for (int n = 0; n < 16; n++) h[n] = 0.f;

    size_t g = (size_t)rowb * 2048 + d;
    float dl = bf2f(delta[g]);
    float uv = bf2f(uc[g]);

#define P1_BODY(DA_STMT)                                                      \
    for (int t = 0; t < TCHUNK; t++) {                                        \
        float dl_n = 0.f, uv_n = 0.f;                                         \
        if (t + 1 < TCHUNK) {                                                 \
            g += 2048;                                                        \
            dl_n = bf2f(delta[g]);                                            \
            uv_n = bf2f(uc[g]);                                               \
        }                                                                     \
        float dlu = dl * uv;                                                  \
        float dAv[16];                                                        \
        DA_STMT;                                                              \
        float bb[16];                                                         \
        {                                                                     \
            const float4* Bv = (const float4*)&Bsh[t * 16];                   \
            *(float4*)&bb[0] = Bv[0]; *(float4*)&bb[4] = Bv[1];               \
            *(float4*)&bb[8] = Bv[2]; *(float4*)&bb[12] = Bv[3];              \
        }                                                                     \
        _Pragma("unroll")                                                     \
        for (int n = 0; n < 16; n++)                                          \
            h[n] = fmaf(dAv[n], h[n], dlu * bb[n]);                           \
        sdl += dl;                                                            \
        dl = dl_n; uv = uv_n;                                                 \
    }

    if (fast) {
        P1_BODY(POW16(dAv, exp2_raw(dl * a0)))
    } else {
        P1_BODY({ _Pragma("unroll") for (int n = 0; n < 16; n++) dAv[n] = exp2_raw(dl * Ac[n]); })
    }
#undef P1_BODY

    size_t base = (((size_t)b * NCHUNK + c) * 16) * 2048 + d;
#pragma unroll
    for (int n = 0; n < 16; n++) {
        Pbuf[base + (size_t)n * 2048] = exp2_raw(Ac[n] * sdl);
        Sbuf[base + (size_t)n * 2048] = h[n];
    }
}

__global__ __launch_bounds__(256) void scan_p2(
    float* __restrict__ Pbuf, const float* __restrict__ Sbuf)
{
    int gid = blockIdx.x * 256 + threadIdx.x;
    int b = gid >> 15;
    int n = (gid >> 11) & 15;
    int d = gid & 2047;
    float hinit = 0.f;
    for (int c = 0; c < NCHUNK; c++) {
        size_t idx = (((size_t)b * NCHUNK + c) * 16 + n) * 2048 + d;
        float p = Pbuf[idx];
        float s = Sbuf[idx];
        Pbuf[idx] = hinit;
        hinit = fmaf(p, hinit, s);
    }
}

__global__ __launch_bounds__(256) void scan_p3(
    const bf16* __restrict__ delta,
    const bf16* uc,
    const bf16* __restrict__ x_dbl,
    const bf16* __restrict__ z,
    const void* __restrict__ A_log_raw,
    const int* __restrict__ flag,
    const bf16* __restrict__ Dvec,
    const float* __restrict__ Hinit,
    bf16* yg)
{
    __shared__ float Bsh[TCHUNK * 16];
    __shared__ float Csh[TCHUNK * 16];
    const int tid = threadIdx.x;
    const int bx = blockIdx.x;
    const int dt = bx & 7;
    const int c = (bx >> 3) & (NCHUNK - 1);
    const int b = bx / (NCHUNK * 8);
    const int d = dt * 256 + tid;
    const int rowb = b * LL + c * TCHUNK;

    if (tid < TCHUNK) {
        float f[16];
        const bf16* p = x_dbl + (size_t)(rowb + tid) * 96 + DT_RANK;
        load8_bf16(p, f);
        load8_bf16(p + 8, f + 8);
#pragma unroll
        for (int n = 0; n < 16; n++) Bsh[tid * 16 + n] = f[n];
        load8_bf16(p + 16, f);
        load8_bf16(p + 24, f + 8);
#pragma unroll
        for (int n = 0; n < 16; n++) Csh[tid * 16 + n] = f[n];
    }

    float Ac[16];   // -exp(A_log) * log2e  (exp2-domain)
    load_Ac(A_log_raw, *flag, d, Ac);
    const float a0 = Ac[0];
    const bool fast = ac_structured(Ac);
    const float Dv = bf2f(Dvec[d]);
    __syncthreads();

    float h[16];
    size_t base = (((size_t)b * NCHUNK + c) * 16) * 2048 + d;
#pragma unroll
    for (int n = 0; n < 16; n++) h[n] = Hinit[base + (size_t)n * 2048];

    size_t g = (size_t)rowb * 2048 + d;
    float dl = bf2f(delta[g]);
    float uv = bf2f(uc[g]);
    float zv = bf2f(z[g]);
    size_t gw = g;

#define P3_BODY(DA_STMT)                                                      \
    for (int t = 0; t < TCHUNK; t++) {                                        \
        float dl_n = 0.f, uv_n = 0.f, zv_n = 0.f;                             \
        if (t + 1 < TCHUNK) {                                                 \
            g += 2048;                                                        \
            dl_n = bf2f(delta[g]);                                            \
            uv_n = bf2f(uc[g]);                                               \
            zv_n = bf2f(z[g]);                                                \
        }                                                                     \
        float dlu = dl * uv;                                                  \
        float dAv[16];                                                        \
        DA_STMT;                                                              \
        float bb[16], cc[16];                                                 \
        {                                                                     \
            const float4* Bv = (const float4*)&Bsh[t * 16];                   \
            const float4* Cv = (const float4*)&Csh[t * 16];                   \
            *(float4*)&bb[0] = Bv[0]; *(float4*)&bb[4] = Bv[1];               \
            *(float4*)&bb[8] = Bv[2]; *(float4*)&bb[12] = Bv[3];              \
            *(float4*)&cc[0] = Cv[0]; *(float4*)&cc[4] = Cv[1];               \
            *(float4*)&cc[8] = Cv[2]; *(float4*)&cc[12] = Cv[3];              \
        }                                                                     \
        float yp0 = 0.f, yp1 = 0.f, yp2 = 0.f, yp3 = 0.f;                     \
        _Pragma("unroll")                                                     \
        for (int n = 0; n < 16; n += 4) {                                     \
            h[n]     = fmaf(dAv[n],     h[n],     dlu * bb[n]);               \
            h[n + 1] = fmaf(dAv[n + 1], h[n + 1], dlu * bb[n + 1]);           \
            h[n + 2] = fmaf(dAv[n + 2], h[n + 2], dlu * bb[n + 2]);           \
            h[n + 3] = fmaf(dAv[n + 3], h[n + 3], dlu * bb[n + 3]);           \
            yp0 = fmaf(h[n],     cc[n],     yp0);                             \
            yp1 = fmaf(h[n + 1], cc[n + 1], yp1);                             \
            yp2 = fmaf(h[n + 2], cc[n + 2], yp2);                             \
            yp3 = fmaf(h[n + 3], cc[n + 3], yp3);                             \
        }                                                                     \
        float y = (yp0 + yp1) + (yp2 + yp3);                                  \
        y = fmaf(uv, Dv, y);                                                  \
        yg[gw] = f2bf(y * silu_f(zv));                                        \
        gw += 2048;                                                           \
        dl = dl_n; uv = uv_n; zv = zv_n;                                      \
    }

    if (fast) {
        P3_BODY(POW16(dAv, exp2_raw(dl * a0)))
    } else {
        P3_BODY({ _Pragma("unroll") for (int n = 0; n < 16; n++) dAv[n] = exp2_raw(dl * Ac[n]); })
    }
#undef P3_BODY
}

// ---------------------------------------------------------------------------
// LayerNorm over last dim (1024). Output dtype per flag (1=fp32, 0=bf16).
// ---------------------------------------------------------------------------
__global__ __launch_bounds__(256) void out_ln(
    const bf16* __restrict__ o,
    const bf16* __restrict__ lw,
    const bf16* __restrict__ lb,
    void* __restrict__ outv,
    const int* __restrict__ flag)
{
    __shared__ float sm[4];
    const int row = blockIdx.x;
    const int tid = threadIdx.x;
    const int lane = tid & 63;
    const int wid = tid >> 6;
    const int c = tid * 4;

    const bf16* rp = o + (size_t)row * 1024 + c;
    float v0 = bf2f(rp[0]), v1 = bf2f(rp[1]), v2 = bf2f(rp[2]), v3 = bf2f(rp[3]);

    float s = v0 + v1 + v2 + v3;
#pragma unroll
    for (int off = 1; off < 64; off <<= 1) s += __shfl_xor(s, off, 64);
    if (lane == 0) sm[wid] = s;
    __syncthreads();
    float mu = (sm[0] + sm[1] + sm[2] + sm[3]) * (1.f / 1024.f);
    __syncthreads();

    float dx0 = v0 - mu, dx1 = v1 - mu, dx2 = v2 - mu, dx3 = v3 - mu;
    float q = dx0 * dx0 + dx1 * dx1 + dx2 * dx2 + dx3 * dx3;
#pragma unroll
    for (int off = 1; off < 64; off <<= 1) q += __shfl_xor(q, off, 64);
    if (lane == 0) sm[wid] = q;
    __syncthreads();
    float var = (sm[0] + sm[1] + sm[2] + sm[3]) * (1.f / 1024.f);
    float inv = rsqrtf(var + 1e-5f);

    float w0 = bf2f(lw[c]), w1 = bf2f(lw[c + 1]), w2 = bf2f(lw[c + 2]), w3 = bf2f(lw[c + 3]);
    float b0 = bf2f(lb[c]), b1 = bf2f(lb[c + 1]), b2 = bf2f(lb[c + 2]), b3 = bf2f(lb[c + 3]);
    float r0 = dx0 * inv * w0 + b0;
    float r1 = dx1 * inv * w1 + b1;
    float r2 = dx2 * inv * w2 + b2;
    float r3 = dx3 * inv * w3 + b3;

    if (*flag) {
        float4* wp = (float4*)((float*)outv + (size_t)row * 1024 + c);
        *wp = make_float4(r0, r1, r2, r3);
    } else {
        bf16* wp = (bf16*)outv + (size_t)row * 1024 + c;
        wp[0] = f2bf(r0); wp[1] = f2bf(r1); wp[2] = f2bf(r2); wp[3] = f2bf(r3);
    }
}

// ---------------------------------------------------------------------------
extern "C" void kernel_launch(void* const* d_in, const int* in_sizes, int n_in,
                              void* d_out, int out_size, void* d_ws, size_t ws_size,
                              hipStream_t stream)
{
    const void* x          = d_in[0];
    const void* in_proj_w  = d_in[1];
    const void* conv_w     = d_in[2];
    const void* conv_b     = d_in[3];
    const void* x_proj_w   = d_in[4];
    const void* dt_proj_w  = d_in[5];
    const void* dt_proj_b  = d_in[6];
    const void* A_log      = d_in[7];
    const void* Dvec       = d_in[8];
    const void* out_proj_w = d_in[9];
    const void* ln_w       = d_in[10];
    const void* ln_b       = d_in[11];

    size_t nBig = (size_t)NROWS * D_INNER;
    size_t xdblN = (size_t)NROWS * 96;
    size_t need = (3 * nBig + xdblN + 196608) * 2;
    if (ws_size < need) {
        hipMemsetAsync(d_out, 0, (size_t)out_size * 2, stream);
        return;
    }

    bf16* bufA = (bf16*)d_ws;       // u -> x_proj_w copy -> delta -> out_proj_w copy
    bf16* bufZ = bufA + nBig;       // z -> y_out
    bf16* bufC = bufZ + nBig;       // x+in_proj_w copies -> u_c / y_gated
    bf16* bufX = bufC + nBig;       // x_dbl
    bf16* bufS = bufX + xdblN;      // flag + small consts

    int*  flag    = (int*)bufS;
    bf16* c_convw = bufS + 16;
    bf16* c_convb = c_convw + 8192;
    bf16* c_dtw   = c_convb + 2048;
    bf16* c_dtb   = c_dtw + 131072;
    bf16* c_Alog  = c_dtb + 2048;
    bf16* c_D     = c_Alog + 32768;
    bf16* c_lnw   = c_D + 2048;
    bf16* c_lnb   = c_lnw + 1024;

    bf16* c_x    = bufC;
    bf16* c_wip  = bufC + (size_t)NROWS * 1024;
    bf16* c_xpw  = bufA;
    bf16* c_opw  = bufA;
    bf16* u      = bufA;
    bf16* delta  = bufA;
    bf16* zbuf   = bufZ;
    bf16* y_out  = bufZ;
    bf16* u_c    = bufC;
    bf16* x_dbl  = bufX;

    // d_out scratch timeline: [x_proj split-K partials 25.2MB] -> [scan P/S
    // 33.5MB] -> [LN output].  No temporal overlap.
    float* Ptmp = (float*)d_out;                      // 4 x 16384 x 96 fp32
    float* Pbuf = (float*)d_out;
    float* Sbuf = Pbuf + (size_t)BB * NCHUNK * 16 * 2048;

    dim3 blk(256);
    auto cvt = [&](const void* src, bf16* dst, int n) {
        convert_to_bf16<<<dim3((n + 255) / 256), blk, 0, stream>>>(src, dst, n, flag);
    };

    // 0. detect input dtype
    detect_dtype<<<dim3(1), blk, 0, stream>>>(x, flag);

    // small consts: one batched dispatch
    {
        CvtBatch b{};
        const void* srcs[8] = {conv_w, conv_b, dt_proj_w, dt_proj_b, A_log, Dvec, ln_w, ln_b};
        bf16* dsts[8] = {c_convw, c_convb, c_dtw, c_dtb, c_Alog, c_D, c_lnw, c_lnb};
        int ns[8] = {D_INNER * 4, D_INNER, D_INNER * DT_RANK, D_INNER,
                     D_INNER * D_STATE, D_INNER, D_MODEL, D_MODEL};
        int acc = 0;
        for (int i = 0; i < 8; i++) {
            b.src[i] = srcs[i]; b.dst[i] = dsts[i]; b.n[i] = ns[i];
            b.blockStart[i] = acc; acc += (ns[i] + 255) / 256;
        }
        b.blockStart[8] = acc; b.count = 8;
        convert_batch<<<dim3(acc), blk, 0, stream>>>(b, flag);
    }

    cvt(x, c_x, NROWS * D_MODEL);
    cvt(in_proj_w, c_wip, 2 * D_INNER * D_MODEL);

    // 1. in_proj: 256x256 kernel, N=4096, split store u | z
    gemm256<2><<<dim3(16 * 64), dim3(512), 0, stream>>>(
        c_x, D_MODEL, c_wip, D_MODEL, D_MODEL, nullptr,
        u, zbuf, D_INNER, /*NBX=*/16, /*Nsplit=*/D_INNER);

    // 2. conv + SiLU -> u_c (bufC copies die here)
    conv_silu<<<dim3((NROWS * D_INNER) / 256), blk, 0, stream>>>(u, u_c, c_convw, c_convb);

    // 3. x_proj (N=96): R7 split-K x4 — grid (4,128) = 512 blocks (full chip)
    //    each covering K=512, fp32 partials in d_out, then combine -> bf16.
    cvt(x_proj_w, c_xpw, 96 * D_INNER);
    gemm_async<3><<<dim3(4, NROWS / 128), blk, 0, stream>>>(
        u_c, D_INNER, c_xpw, D_INNER, D_INNER / 4, nullptr,
        (bf16*)Ptmp, nullptr, 96, 96, /*Mrows=*/NROWS);
    combine_splitk<<<dim3((NROWS * 96 + 255) / 256), blk, 0, stream>>>(
        Ptmp, x_dbl, NROWS * 96, NROWS * 96);

    // 4. dt_proj + softplus -> delta: 256² kernel, NT=1, softplus epilogue
    gemm256<1><<<dim3(8 * 64), dim3(512), 0, stream>>>(
        x_dbl, 96, c_dtw, DT_RANK, DT_RANK, c_dtb,
        delta, nullptr, D_INNER, /*NBX=*/8, /*Nsplit=*/0);

    // 5. chunked selective scan (3 phases), gate fused; in-place into u_c
    scan_p1<<<dim3(BB * NCHUNK * 8), blk, 0, stream>>>(
        delta, u_c, x_dbl, A_log, flag, Pbuf, Sbuf);
    scan_p2<<<dim3(BB * 16 * 2048 / 256), blk, 0, stream>>>(Pbuf, Sbuf);
    scan_p3<<<dim3(BB * NCHUNK * 8), blk, 0, stream>>>(
        delta, u_c, x_dbl, zbuf, A_log, flag, c_D, Pbuf, u_c);

    // 6. out_proj -> y_out in bufZ: 256x256 kernel
    cvt(out_proj_w, c_opw, D_MODEL * D_INNER);
    gemm256<0><<<dim3(4 * 64), dim3(512), 0, stream>>>(
        u_c, D_INNER, c_opw, D_INNER, D_INNER, nullptr,
        y_out, nullptr, D_MODEL, /*NBX=*/4, /*Nsplit=*/0);

    // 7. LayerNorm -> d_out
    out_ln<<<dim3(NROWS), blk, 0, stream>>>(y_out, c_lnw, c_lnb, d_out, flag);
}

// Round 9
// 819.455 us; speedup vs baseline: 1.3230x; 1.3230x over previous
//
#include <hip/hip_runtime.h>
#include <hip/hip_bf16.h>
#include <math.h>

#define D_MODEL 1024
#define D_INNER 2048
#define D_STATE 16
#define DT_RANK 64
#define BB 4
#define LL 4096
#define NROWS (BB * LL)   // 16384
#define NCHUNK 32
#define TCHUNK 128        // NCHUNK * TCHUNK == LL

typedef __hip_bfloat16 bf16;
typedef __attribute__((ext_vector_type(8))) short short8;   // MFMA A/B frag (8 bf16)
typedef __attribute__((ext_vector_type(4))) float floatx4;  // MFMA C/D frag

__device__ __forceinline__ float silu_f(float x) { return x / (1.f + __expf(-x)); }
__device__ __forceinline__ float softplus_f(float x) { return x > 20.f ? x : log1pf(__expf(x)); }
__device__ __forceinline__ float bf2f(bf16 v) { return __bfloat162float(v); }
__device__ __forceinline__ bf16 f2bf(float v) { return __float2bfloat16(v); }

// raw v_exp_f32 (2^x). Callers pre-fold the log2e factor into the operand.
__device__ __forceinline__ float exp2_raw(float x) {
    float r;
    asm("v_exp_f32 %0, %1" : "=v"(r) : "v"(x));
    return r;
}

// async 16B global -> LDS copy (gfx950 global_load_lds_dwordx4).
// HW semantics: LDS dest = wave-uniform base + lane*16 [m97/m104].
__device__ __forceinline__ void gl2lds16(const bf16* g, short* lds) {
    __builtin_amdgcn_global_load_lds(
        (const __attribute__((address_space(1))) void*)g,
        (__attribute__((address_space(3))) void*)lds, 16, 0, 0);
}

// decode 8 consecutive bf16 (16-byte aligned) to fp32
__device__ __forceinline__ void load8_bf16(const bf16* p, float* f) {
    uint4 raw = *(const uint4*)p;
    unsigned int w0 = raw.x, w1 = raw.y, w2 = raw.z, w3 = raw.w;
    f[0] = __uint_as_float((w0 & 0xffffu) << 16);
    f[1] = __uint_as_float(w0 & 0xffff0000u);
    f[2] = __uint_as_float((w1 & 0xffffu) << 16);
    f[3] = __uint_as_float(w1 & 0xffff0000u);
    f[4] = __uint_as_float((w2 & 0xffffu) << 16);
    f[5] = __uint_as_float(w2 & 0xffff0000u);
    f[6] = __uint_as_float((w3 & 0xffffu) << 16);
    f[7] = __uint_as_float(w3 & 0xffff0000u);
}

// ---------------------------------------------------------------------------
// Input dtype detection (1 = fp32 inputs, 0 = bf16 inputs).
// ---------------------------------------------------------------------------
__global__ void detect_dtype(const void* xsrc, int* flag) {
    const unsigned short* p = (const unsigned short*)xsrc;
    int tid = threadIdx.x;
    int bad = 0;
    for (int i = tid; i < 2048; i += 256) {
        float v = __uint_as_float(((unsigned int)p[i]) << 16);
        if (!isfinite(v) || fabsf(v) > 1e6f) bad = 1;
    }
    __shared__ int sbad;
    if (tid == 0) sbad = 0;
    __syncthreads();
    if (bad) atomicOr(&sbad, 1);
    __syncthreads();
    if (tid == 0) *flag = sbad;
}

__global__ __launch_bounds__(256) void convert_to_bf16(
    const void* __restrict__ src, bf16* __restrict__ dst, int n,
    const int* __restrict__ flag)
{
    int i = blockIdx.x * 256 + threadIdx.x;
    if (i >= n) return;
    if (*flag)
        dst[i] = f2bf(((const float*)src)[i]);
    else
        dst[i] = ((const bf16*)src)[i];
}

// batch of small conversions in a single dispatch (saves ~7 launches)
struct CvtBatch {
    const void* src[8];
    bf16* dst[8];
    int n[8];
    int blockStart[9];   // prefix of ceil(n/256)
    int count;
};
__global__ __launch_bounds__(256) void convert_batch(CvtBatch b, const int* __restrict__ flag) {
    int bi = blockIdx.x;
    int seg = 0;
    while (seg + 1 < b.count && bi >= b.blockStart[seg + 1]) seg++;
    int i = (bi - b.blockStart[seg]) * 256 + threadIdx.x;
    if (i >= b.n[seg]) return;
    if (*flag)
        b.dst[seg][i] = f2bf(((const float*)b.src[seg])[i]);
    else
        b.dst[seg][i] = ((const bf16*)b.src[seg])[i];
}

// combine 4 split-K fp32 partials -> bf16 (coalesced: 1 elem/thread)
__global__ __launch_bounds__(256) void combine_splitk(
    const float* __restrict__ p, bf16* __restrict__ out, int n, int stride)
{
    int i = blockIdx.x * 256 + threadIdx.x;
    if (i >= n) return;
    float v = (p[i] + p[i + (size_t)stride]) +
              (p[i + 2 * (size_t)stride] + p[i + 3 * (size_t)stride]);
    out[i] = f2bf(v);
}

// ---------------------------------------------------------------------------
// Legacy 128x128 async-staged MFMA GEMM (m97 structure).
// EPI: 0 plain, 1 softplus+bias, 2 split store, 3 split-K fp32 partials
// (x_proj was 128 blocks = half-chip-idle with a 64-deep serial K chain;
//  EPI=3 uses blockIdx.x as the K-slice: grid (KS, M/128), each block does
//  K columns starting at slice*K, storing fp32 partials to
//  (float*)C + (slice*Mrows + row)*ldc + col.  Mrows passed via Nsplit.)
// ---------------------------------------------------------------------------
template <int EPI>
__global__ __launch_bounds__(256) void gemm_async(
    const bf16* __restrict__ A, int lda,
    const bf16* __restrict__ W, int ldw, int K,
    const bf16* __restrict__ bias,
    bf16* __restrict__ C, bf16* __restrict__ C2, int ldc,
    int N, int Nsplit)
{
    __shared__ short As[128 * 32];   // [m][k], 8 KB
    __shared__ short Bs[128 * 32];   // [n][k], 8 KB

    const int tid = threadIdx.x;
    const int m0 = blockIdx.y * 128;
    const int n0 = (EPI == 3) ? 0 : blockIdx.x * 128;
    const int ks = (EPI == 3) ? (int)blockIdx.x * K : 0;   // K-slice offset
    const int wid = tid >> 6;
    const int lane = tid & 63;
    const int wm = wid & 1;
    const int wn = wid >> 1;
    const int lm = lane & 15;
    const int quad = lane >> 4;

    floatx4 acc[4][4];
#pragma unroll
    for (int i = 0; i < 4; i++)
#pragma unroll
        for (int j = 0; j < 4; j++) acc[i][j] = (floatx4){0.f, 0.f, 0.f, 0.f};

    for (int k0 = 0; k0 < K; k0 += 32) {
#pragma unroll
        for (int j = 0; j < 2; j++) {
            int cbase = (wid * 2 + j) * 64;       // wave-uniform
            int c = cbase + lane;
            int row = c >> 2, seg = c & 3;
            gl2lds16(A + (size_t)(m0 + row) * lda + ks + k0 + seg * 8, &As[cbase * 8]);
        }
#pragma unroll
        for (int j = 0; j < 2; j++) {
            int cbase = (wid * 2 + j) * 64;
            int c = cbase + lane;
            int row = c >> 2, seg = c & 3;
            int wrow = n0 + row; if (wrow >= N) wrow = N - 1;
            gl2lds16(W + (size_t)wrow * ldw + ks + k0 + seg * 8, &Bs[cbase * 8]);
        }
        __syncthreads();

        short8 af[4], bfr[4];
#pragma unroll
        for (int mt = 0; mt < 4; mt++)
            af[mt] = *(const short8*)&As[(wm * 64 + mt * 16 + lm) * 32 + quad * 8];
#pragma unroll
        for (int nt = 0; nt < 4; nt++)
            bfr[nt] = *(const short8*)&Bs[(wn * 64 + nt * 16 + lm) * 32 + quad * 8];
        __syncthreads();

#pragma unroll
        for (int mt = 0; mt < 4; mt++)
#pragma unroll
            for (int nt = 0; nt < 4; nt++)
                acc[mt][nt] = __builtin_amdgcn_mfma_f32_16x16x32_bf16(
                    af[mt], bfr[nt], acc[mt][nt], 0, 0, 0);
    }

#pragma unroll
    for (int mt = 0; mt < 4; mt++) {
#pragma unroll
        for (int nt = 0; nt < 4; nt++) {
            int col = n0 + wn * 64 + nt * 16 + lm;
            if (col >= N) continue;
            int rbase = m0 + wm * 64 + mt * 16 + quad * 4;
#pragma unroll
            for (int r = 0; r < 4; r++) {
                float v = acc[mt][nt][r];
                if (EPI == 3) {
                    ((float*)C)[((size_t)blockIdx.x * Nsplit + rbase + r) * ldc + col] = v;
                } else if (EPI == 1) {
                    C[(size_t)(rbase + r) * ldc + col] = f2bf(softplus_f(v + bf2f(bias[col])));
                } else if (EPI == 2) {
                    if (col < Nsplit)
                        C[(size_t)(rbase + r) * ldc + col] = f2bf(v);
                    else
                        C2[(size_t)(rbase + r) * ldc + (col - Nsplit)] = f2bf(v);
                } else {
                    C[(size_t)(rbase + r) * ldc + col] = f2bf(v);
                }
            }
        }
    }
}

// ---------------------------------------------------------------------------
// 256x256 MFMA GEMM, R2 structure: all-reads-up-front + 2 barriers/K-tile.
// C[M,N] = A[M,K] @ W[N,K]^T.  Requires M%256==0, N%256==0, K%64==0, K>=64
// (NT=1 degenerates cleanly).  EPI: 0 plain, 1 softplus+bias, 2 split.
// R8 post-mortem: the by-fastest XCD mapping regressed dt_proj 3x for
// reasons the wg%8=XCD model cannot explain -> assignment model unverified.
// REVERTED to the R7 swizzle (proven 824 us config).
// ---------------------------------------------------------------------------
template <int EPI>
__global__ __launch_bounds__(512, 2) void gemm256(
    const bf16* __restrict__ A, int lda,
    const bf16* __restrict__ W, int ldw, int K,
    const bf16* __restrict__ bias,
    bf16* __restrict__ C, bf16* __restrict__ C2, int ldc,
    int NBX, int Nsplit)
{
    __shared__ short lds[65536];   // 128 KB: [buf][A 16384 | B 16384] shorts

    const int tid = threadIdx.x;
    const int wid = tid >> 6;
    const int lane = tid & 63;
    const int lm = lane & 15;
    const int quad = lane >> 4;
    const int wm = wid >> 2;      // 0..1
    const int wn = wid & 3;       // 0..3

    // XCD-aware bijective swizzle (caller guarantees nwg % 8 == 0) — R7 form
    const int nwg = (int)gridDim.x;
    const int wg = (int)blockIdx.x;
    const int swz = (wg & 7) * (nwg >> 3) + (wg >> 3);
    const int by = swz / NBX;
    const int bx = swz - by * NBX;
    const int m0 = by * 256;
    const int n0 = bx * 256;

    const int NT = K >> 6;

    floatx4 acc[2][4][2][2];
#pragma unroll
    for (int a = 0; a < 2; a++)
#pragma unroll
        for (int b = 0; b < 4; b++)
#pragma unroll
            for (int c = 0; c < 2; c++)
#pragma unroll
                for (int d = 0; d < 2; d++) acc[a][b][c][d] = (floatx4){0.f, 0.f, 0.f, 0.f};

    // stage one 16 KB half of the A (resp. B) tile of K-step t_ into buffer bsel.
    auto stageA = [&](int bsel, int t_, int half) {
        short* base = &lds[bsel * 32768];
        const bf16* g = A + (size_t)m0 * lda + t_ * 64;
#pragma unroll
        for (int part = 0; part < 2; part++) {
            int cbase = half * 512 + part * 1024 + wid * 64;   // wave-uniform
            int c = cbase + lane;
            int row = c >> 3;
            int gs = (c & 7) ^ (row & 7);                      // inverse swizzle on source
            gl2lds16(g + (size_t)row * lda + gs * 8, base + cbase * 8);
        }
    };
    auto stageB = [&](int bsel, int t_, int half) {
        short* base = &lds[bsel * 32768 + 16384];
        const bf16* g = W + (size_t)n0 * ldw + t_ * 64;
#pragma unroll
        for (int part = 0; part < 2; part++) {
            int cbase = half * 1024 + part * 512 + wid * 64;
            int c = cbase + lane;
            int row = c >> 3;
            int gs = (c & 7) ^ (row & 7);
            gl2lds16(g + (size_t)row * ldw + gs * 8, base + cbase * 8);
        }
    };

    // ---- prologue
    stageA(0, 0, 0); stageA(0, 0, 1); stageB(0, 0, 0); stageB(0, 0, 1);
    if (NT > 1) { stageA(1, 1, 0); stageB(1, 1, 1); }
    if (NT > 1) asm volatile("s_waitcnt vmcnt(4)" ::: "memory");
    else        asm volatile("s_waitcnt vmcnt(0)" ::: "memory");
    __builtin_amdgcn_s_barrier();

#define READ_A(DST, MH)                                                         \
    _Pragma("unroll")                                                           \
    for (int mt = 0; mt < 4; mt++) {                                            \
        int r = wm * 128 + (MH) * 64 + mt * 16 + lm;                            \
        _Pragma("unroll")                                                       \
        for (int kk = 0; kk < 2; kk++)                                          \
            DST[mt][kk] = *(const short8*)&As_[r * 64 + (((kk * 4 + quad) ^ (r & 7)) * 8)]; \
    }
#define READ_B(DST, NH)                                                         \
    _Pragma("unroll")                                                           \
    for (int nf = 0; nf < 2; nf++) {                                            \
        int r = (NH) * 128 + wn * 32 + nf * 16 + lm;                            \
        _Pragma("unroll")                                                       \
        for (int kk = 0; kk < 2; kk++)                                          \
            DST[nf][kk] = *(const short8*)&Bs_[r * 64 + (((kk * 4 + quad) ^ (r & 7)) * 8)]; \
    }
#define MFMA16(AF, BV, MH, NH)                                                  \
    __builtin_amdgcn_s_setprio(1);                                              \
    _Pragma("unroll")                                                           \
    for (int mt = 0; mt < 4; mt++)                                              \
        _Pragma("unroll")                                                       \
        for (int nf = 0; nf < 2; nf++)                                          \
            _Pragma("unroll")                                                   \
            for (int kk = 0; kk < 2; kk++)                                      \
                acc[MH][mt][NH][nf] = __builtin_amdgcn_mfma_f32_16x16x32_bf16(  \
                    AF[mt][kk], BV[nf][kk], acc[MH][mt][NH][nf], 0, 0, 0);      \
    __builtin_amdgcn_s_setprio(0);

    for (int t = 0; t < NT; t++) {
        const int buf = t & 1;
        const int bufn = buf ^ 1;
        short* As_ = &lds[buf * 32768];
        short* Bs_ = &lds[buf * 32768 + 16384];
        short8 af0[4][2], af1[4][2], bv0[2][2], bv1[2][2];

        READ_A(af0, 0)
        READ_B(bv0, 0)
        READ_B(bv1, 1)
        READ_A(af1, 1)

        if (t + 1 < NT) { stageA(bufn, t + 1, 1); stageB(bufn, t + 1, 0); }

        MFMA16(af0, bv0, 0, 0)
        MFMA16(af0, bv1, 0, 1)

        __builtin_amdgcn_s_barrier();   // #1

        if (t + 2 < NT) { stageA(buf, t + 2, 0); stageB(buf, t + 2, 1); }

        MFMA16(af1, bv1, 1, 1)
        MFMA16(af1, bv0, 1, 0)

        if (t + 2 < NT)      { asm volatile("s_waitcnt vmcnt(4)" ::: "memory"); }
        else if (t + 1 < NT) { asm volatile("s_waitcnt vmcnt(0)" ::: "memory"); }
        __builtin_amdgcn_s_barrier();   // #2
    }
#undef READ_A
#undef READ_B
#undef MFMA16

    // epilogue: C/D layout col = lane&15, row = quad*4 + r  [m89/m91]
#pragma unroll
    for (int mh = 0; mh < 2; mh++)
#pragma unroll
        for (int mt = 0; mt < 4; mt++)
#pragma unroll
            for (int nh = 0; nh < 2; nh++)
#pragma unroll
                for (int nf = 0; nf < 2; nf++) {
                    int col = n0 + nh * 128 + wn * 32 + nf * 16 + lm;
                    int rbase = m0 + wm * 128 + mh * 64 + mt * 16 + quad * 4;
#pragma unroll
                    for (int r = 0; r < 4; r++) {
                        float v = acc[mh][mt][nh][nf][r];
                        if (EPI == 1) v = softplus_f(v + bf2f(bias[col]));
                        if (EPI == 2) {
                            if (col < Nsplit)
                                C[(size_t)(rbase + r) * ldc + col] = f2bf(v);
                            else
                                C2[(size_t)(rbase + r) * ldc + (col - Nsplit)] = f2bf(v);
                        } else {
                            C[(size_t)(rbase + r) * ldc + col] = f2bf(v);
                        }
                    }
                }
}

// ---------------------------------------------------------------------------
// Causal depthwise conv1d (width 4) + bias + SiLU. bf16 in/out, fp32 math.
// ---------------------------------------------------------------------------
__global__ __launch_bounds__(256) void conv_silu(
    const bf16* __restrict__ u,
    bf16* __restrict__ u_c,
    const bf16* __restrict__ w,
    const bf16* __restrict__ bias)
{
    int gid = blockIdx.x * 256 + threadIdx.x;
    if (gid >= NROWS * D_INNER) return;
    int d = gid & (D_INNER - 1);
    int row = gid >> 11;
    int l = row & (LL - 1);
    float acc = bf2f(bias[d]);
#pragma unroll
    for (int t = 0; t < 4; t++) {
        int ls = l - 3 + t;
        if (ls >= 0)
            acc = fmaf(bf2f(w[d * 4 + t]), bf2f(u[(size_t)(row - 3 + t) * D_INNER + d]), acc);
    }
    u_c[(size_t)row * D_INNER + d] = f2bf(silu_f(acc));
}

// ---------------------------------------------------------------------------
// Chunked selective scan (3 phases).  R6: A_log read in original precision
// so the POW16 structure check passes (bf16 copy failed the 1e-4 check).
// ---------------------------------------------------------------------------

// dA[0..15] = q^(n+1), 15 muls, depth ~4
#define POW16(DA, Q) do {                                                     \
    float q1 = (Q);                                                           \
    float q2 = q1 * q1;                                                       \
    float q3 = q2 * q1;                                                       \
    float q4 = q2 * q2;                                                       \
    float q8 = q4 * q4;                                                       \
    DA[0] = q1;       DA[1] = q2;       DA[2] = q3;       DA[3] = q4;         \
    DA[4] = q4 * q1;  DA[5] = q4 * q2;  DA[6] = q4 * q3;  DA[7] = q8;         \
    DA[8] = q8 * q1;  DA[9] = q8 * q2;  DA[10] = q8 * q3; DA[11] = q8 * q4;   \
    DA[12] = q8 * DA[4]; DA[13] = q8 * DA[5]; DA[14] = q8 * DA[6];            \
    DA[15] = q8 * q8;                                                         \
} while (0)

__device__ __forceinline__ bool ac_structured(const float* Ac) {
    float a0 = Ac[0];
    bool ok = true;
#pragma unroll
    for (int n = 1; n < 16; n++) {
        float want = (float)(n + 1) * a0;
        ok = ok && (fabsf(Ac[n] - want) <= 1e-4f * fabsf(want) + 1e-12f);
    }
    return ok;
}

// load A_log row d (16 values) in original precision, produce exp2-domain Ac
__device__ __forceinline__ void load_Ac(const void* A_log_raw, int fp32, int d, float* Ac) {
    float f[16];
    if (fp32) {
        const float* ap = (const float*)A_log_raw + (size_t)d * 16;
#pragma unroll
        for (int n = 0; n < 16; n++) f[n] = ap[n];
    } else {
        const bf16* ap = (const bf16*)A_log_raw + (size_t)d * 16;
        load8_bf16(ap, f);
        load8_bf16(ap + 8, f + 8);
    }
#pragma unroll
    for (int n = 0; n < 16; n++) Ac[n] = -__expf(f[n]) * 1.4426950408889634f;
}

__global__ __launch_bounds__(256) void scan_p1(
    const bf16* __restrict__ delta,
    const bf16* __restrict__ uc,
    const bf16* __restrict__ x_dbl,
    const void* __restrict__ A_log_raw,
    const int* __restrict__ flag,
    float* __restrict__ Pbuf, float* __restrict__ Sbuf)
{
    __shared__ float Bsh[TCHUNK * 16];
    const int tid = threadIdx.x;
    const int bx = blockIdx.x;
    const int dt = bx & 7;
    const int c = (bx >> 3) & (NCHUNK - 1);
    const int b = bx / (NCHUNK * 8);
    const int d = dt * 256 + tid;
    const int rowb = b * LL + c * TCHUNK;

    if (tid < TCHUNK) {
        float f[16];
        const bf16* p = x_dbl + (size_t)(rowb + tid) * 96 + DT_RANK;
        load8_bf16(p, f);
        load8_bf16(p + 8, f + 8);
#pragma unroll
        for (int n = 0; n < 16; n++) Bsh[tid * 16 + n] = f[n];
    }

    float Ac[16];   // -exp(A_log) * log2e  (exp2-domain)
    load_Ac(A_log_raw, *flag, d, Ac);
    const float a0 = Ac[0];
    const bool fast = ac_structured(Ac);
    __syncthreads();

    float h[16];
    float sdl = 0.f;   // sum of dl over chunk -> Pp via exp2(Ac*sdl)
#pragma unroll
    for (int n = 0; n < 16; n++) h[n] = 0.f;

    size_t g = (size_t)rowb * 2048 + d;
    float dl = bf2f(delta[g]);
    float uv = bf2f(uc[g]);

#define P1_BODY(DA_STMT)                                                      \
    for (int t = 0; t < TCHUNK; t++) {                                        \
        float dl_n = 0.f, uv_n = 0.f;                                         \
        if (t + 1 < TCHUNK) {                                                 \
            g += 2048;                                                        \
            dl_n = bf2f(delta[g]);                                            \
            uv_n = bf2f(uc[g]);                                               \
        }                                                                     \
        float dlu = dl * uv;                                                  \
        float dAv[16];                                                        \
        DA_STMT;                                                              \
        float bb[16];                                                         \
        {                                                                     \
            const float4* Bv = (const float4*)&Bsh[t * 16];                   \
            *(float4*)&bb[0] = Bv[0]; *(float4*)&bb[4] = Bv[1];               \
            *(float4*)&bb[8] = Bv[2]; *(float4*)&bb[12] = Bv[3];              \
        }                                                                     \
        _Pragma("unroll")                                                     \
        for (int n = 0; n < 16; n++)                                          \
            h[n] = fmaf(dAv[n], h[n], dlu * bb[n]);                           \
        sdl += dl;                                                            \
        dl = dl_n; uv = uv_n;                                                 \
    }

    if (fast) {
        P1_BODY(POW16(dAv, exp2_raw(dl * a0)))
    } else {
        P1_BODY({ _Pragma("unroll") for (int n = 0; n < 16; n++) dAv[n] = exp2_raw(dl * Ac[n]); })
    }
#undef P1_BODY

    size_t base = (((size_t)b * NCHUNK + c) * 16) * 2048 + d;
#pragma unroll
    for (int n = 0; n < 16; n++) {
        Pbuf[base + (size_t)n * 2048] = exp2_raw(Ac[n] * sdl);
        Sbuf[base + (size_t)n * 2048] = h[n];
    }
}

__global__ __launch_bounds__(256) void scan_p2(
    float* __restrict__ Pbuf, const float* __restrict__ Sbuf)
{
    int gid = blockIdx.x * 256 + threadIdx.x;
    int b = gid >> 15;
    int n = (gid >> 11) & 15;
    int d = gid & 2047;
    float hinit = 0.f;
    for (int c = 0; c < NCHUNK; c++) {
        size_t idx = (((size_t)b * NCHUNK + c) * 16 + n) * 2048 + d;
        float p = Pbuf[idx];
        float s = Sbuf[idx];
        Pbuf[idx] = hinit;
        hinit = fmaf(p, hinit, s);
    }
}

__global__ __launch_bounds__(256) void scan_p3(
    const bf16* __restrict__ delta,
    const bf16* uc,
    const bf16* __restrict__ x_dbl,
    const bf16* __restrict__ z,
    const void* __restrict__ A_log_raw,
    const int* __restrict__ flag,
    const bf16* __restrict__ Dvec,
    const float* __restrict__ Hinit,
    bf16* yg)
{
    __shared__ float Bsh[TCHUNK * 16];
    __shared__ float Csh[TCHUNK * 16];
    const int tid = threadIdx.x;
    const int bx = blockIdx.x;
    const int dt = bx & 7;
    const int c = (bx >> 3) & (NCHUNK - 1);
    const int b = bx / (NCHUNK * 8);
    const int d = dt * 256 + tid;
    const int rowb = b * LL + c * TCHUNK;

    if (tid < TCHUNK) {
        float f[16];
        const bf16* p = x_dbl + (size_t)(rowb + tid) * 96 + DT_RANK;
        load8_bf16(p, f);
        load8_bf16(p + 8, f + 8);
#pragma unroll
        for (int n = 0; n < 16; n++) Bsh[tid * 16 + n] = f[n];
        load8_bf16(p + 16, f);
        load8_bf16(p + 24, f + 8);
#pragma unroll
        for (int n = 0; n < 16; n++) Csh[tid * 16 + n] = f[n];
    }

    float Ac[16];   // -exp(A_log) * log2e  (exp2-domain)
    load_Ac(A_log_raw, *flag, d, Ac);
    const float a0 = Ac[0];
    const bool fast = ac_structured(Ac);
    const float Dv = bf2f(Dvec[d]);
    __syncthreads();

    float h[16];
    size_t base = (((size_t)b * NCHUNK + c) * 16) * 2048 + d;
#pragma unroll
    for (int n = 0; n < 16; n++) h[n] = Hinit[base + (size_t)n * 2048];

    size_t g = (size_t)rowb * 2048 + d;
    float dl = bf2f(delta[g]);
    float uv = bf2f(uc[g]);
    float zv = bf2f(z[g]);
    size_t gw = g;

#define P3_BODY(DA_STMT)                                                      \
    for (int t = 0; t < TCHUNK; t++) {                                        \
        float dl_n = 0.f, uv_n = 0.f, zv_n = 0.f;                             \
        if (t + 1 < TCHUNK) {                                                 \
            g += 2048;                                                        \
            dl_n = bf2f(delta[g]);                                            \
            uv_n = bf2f(uc[g]);                                               \
            zv_n = bf2f(z[g]);                                                \
        }                                                                     \
        float dlu = dl * uv;                                                  \
        float dAv[16];                                                        \
        DA_STMT;                                                              \
        float bb[16], cc[16];                                                 \
        {                                                                     \
            const float4* Bv = (const float4*)&Bsh[t * 16];                   \
            const float4* Cv = (const float4*)&Csh[t * 16];                   \
            *(float4*)&bb[0] = Bv[0]; *(float4*)&bb[4] = Bv[1];               \
            *(float4*)&bb[8] = Bv[2]; *(float4*)&bb[12] = Bv[3];              \
            *(float4*)&cc[0] = Cv[0]; *(float4*)&cc[4] = Cv[1];               \
            *(float4*)&cc[8] = Cv[2]; *(float4*)&cc[12] = Cv[3];              \
        }                                                                     \
        float yp0 = 0.f, yp1 = 0.f, yp2 = 0.f, yp3 = 0.f;                     \
        _Pragma("unroll")                                                     \
        for (int n = 0; n < 16; n += 4) {                                     \
            h[n]     = fmaf(dAv[n],     h[n],     dlu * bb[n]);               \
            h[n + 1] = fmaf(dAv[n + 1], h[n + 1], dlu * bb[n + 1]);           \
            h[n + 2] = fmaf(dAv[n + 2], h[n + 2], dlu * bb[n + 2]);           \
            h[n + 3] = fmaf(dAv[n + 3], h[n + 3], dlu * bb[n + 3]);           \
            yp0 = fmaf(h[n],     cc[n],     yp0);                             \
            yp1 = fmaf(h[n + 1], cc[n + 1], yp1);                             \
            yp2 = fmaf(h[n + 2], cc[n + 2], yp2);                             \
            yp3 = fmaf(h[n + 3], cc[n + 3], yp3);                             \
        }                                                                     \
        float y = (yp0 + yp1) + (yp2 + yp3);                                  \
        y = fmaf(uv, Dv, y);                                                  \
        yg[gw] = f2bf(y * silu_f(zv));                                        \
        gw += 2048;                                                           \
        dl = dl_n; uv = uv_n; zv = zv_n;                                      \
    }

    if (fast) {
        P3_BODY(POW16(dAv, exp2_raw(dl * a0)))
    } else {
        P3_BODY({ _Pragma("unroll") for (int n = 0; n < 16; n++) dAv[n] = exp2_raw(dl * Ac[n]); })
    }
#undef P3_BODY
}

// ---------------------------------------------------------------------------
// LayerNorm over last dim (1024). Output dtype per flag (1=fp32, 0=bf16).
// ---------------------------------------------------------------------------
__global__ __launch_bounds__(256) void out_ln(
    const bf16* __restrict__ o,
    const bf16* __restrict__ lw,
    const bf16* __restrict__ lb,
    void* __restrict__ outv,
    const int* __restrict__ flag)
{
    __shared__ float sm[4];
    const int row = blockIdx.x;
    const int tid = threadIdx.x;
    const int lane = tid & 63;
    const int wid = tid >> 6;
    const int c = tid * 4;

    const bf16* rp = o + (size_t)row * 1024 + c;
    float v0 = bf2f(rp[0]), v1 = bf2f(rp[1]), v2 = bf2f(rp[2]), v3 = bf2f(rp[3]);

    float s = v0 + v1 + v2 + v3;
#pragma unroll
    for (int off = 1; off < 64; off <<= 1) s += __shfl_xor(s, off, 64);
    if (lane == 0) sm[wid] = s;
    __syncthreads();
    float mu = (sm[0] + sm[1] + sm[2] + sm[3]) * (1.f / 1024.f);
    __syncthreads();

    float dx0 = v0 - mu, dx1 = v1 - mu, dx2 = v2 - mu, dx3 = v3 - mu;
    float q = dx0 * dx0 + dx1 * dx1 + dx2 * dx2 + dx3 * dx3;
#pragma unroll
    for (int off = 1; off < 64; off <<= 1) q += __shfl_xor(q, off, 64);
    if (lane == 0) sm[wid] = q;
    __syncthreads();
    float var = (sm[0] + sm[1] + sm[2] + sm[3]) * (1.f / 1024.f);
    float inv = rsqrtf(var + 1e-5f);

    float w0 = bf2f(lw[c]), w1 = bf2f(lw[c + 1]), w2 = bf2f(lw[c + 2]), w3 = bf2f(lw[c + 3]);
    float b0 = bf2f(lb[c]), b1 = bf2f(lb[c + 1]), b2 = bf2f(lb[c + 2]), b3 = bf2f(lb[c + 3]);
    float r0 = dx0 * inv * w0 + b0;
    float r1 = dx1 * inv * w1 + b1;
    float r2 = dx2 * inv * w2 + b2;
    float r3 = dx3 * inv * w3 + b3;

    if (*flag) {
        float4* wp = (float4*)((float*)outv + (size_t)row * 1024 + c);
        *wp = make_float4(r0, r1, r2, r3);
    } else {
        bf16* wp = (bf16*)outv + (size_t)row * 1024 + c;
        wp[0] = f2bf(r0); wp[1] = f2bf(r1); wp[2] = f2bf(r2); wp[3] = f2bf(r3);
    }
}

// ---------------------------------------------------------------------------
extern "C" void kernel_launch(void* const* d_in, const int* in_sizes, int n_in,
                              void* d_out, int out_size, void* d_ws, size_t ws_size,
                              hipStream_t stream)
{
    const void* x          = d_in[0];
    const void* in_proj_w  = d_in[1];
    const void* conv_w     = d_in[2];
    const void* conv_b     = d_in[3];
    const void* x_proj_w   = d_in[4];
    const void* dt_proj_w  = d_in[5];
    const void* dt_proj_b  = d_in[6];
    const void* A_log      = d_in[7];
    const void* Dvec       = d_in[8];
    const void* out_proj_w = d_in[9];
    const void* ln_w       = d_in[10];
    const void* ln_b       = d_in[11];

    size_t nBig = (size_t)NROWS * D_INNER;
    size_t xdblN = (size_t)NROWS * 96;
    size_t need = (3 * nBig + xdblN + 196608) * 2;
    if (ws_size < need) {
        hipMemsetAsync(d_out, 0, (size_t)out_size * 2, stream);
        return;
    }

    bf16* bufA = (bf16*)d_ws;       // u -> x_proj_w copy -> delta -> out_proj_w copy
    bf16* bufZ = bufA + nBig;       // z -> y_out
    bf16* bufC = bufZ + nBig;       // x+in_proj_w copies -> u_c / y_gated
    bf16* bufX = bufC + nBig;       // x_dbl
    bf16* bufS = bufX + xdblN;      // flag + small consts

    int*  flag    = (int*)bufS;
    bf16* c_convw = bufS + 16;
    bf16* c_convb = c_convw + 8192;
    bf16* c_dtw   = c_convb + 2048;
    bf16* c_dtb   = c_dtw + 131072;
    bf16* c_Alog  = c_dtb + 2048;
    bf16* c_D     = c_Alog + 32768;
    bf16* c_lnw   = c_D + 2048;
    bf16* c_lnb   = c_lnw + 1024;

    bf16* c_x    = bufC;
    bf16* c_wip  = bufC + (size_t)NROWS * 1024;
    bf16* c_xpw  = bufA;
    bf16* c_opw  = bufA;
    bf16* u      = bufA;
    bf16* delta  = bufA;
    bf16* zbuf   = bufZ;
    bf16* y_out  = bufZ;
    bf16* u_c    = bufC;
    bf16* x_dbl  = bufX;

    // d_out scratch timeline: [x_proj split-K partials 25.2MB] -> [scan P/S
    // 33.5MB] -> [LN output].  No temporal overlap.
    float* Ptmp = (float*)d_out;                      // 4 x 16384 x 96 fp32
    float* Pbuf = (float*)d_out;
    float* Sbuf = Pbuf + (size_t)BB * NCHUNK * 16 * 2048;

    dim3 blk(256);
    auto cvt = [&](const void* src, bf16* dst, int n) {
        convert_to_bf16<<<dim3((n + 255) / 256), blk, 0, stream>>>(src, dst, n, flag);
    };

    // 0. detect input dtype
    detect_dtype<<<dim3(1), blk, 0, stream>>>(x, flag);

    // small consts: one batched dispatch
    {
        CvtBatch b{};
        const void* srcs[8] = {conv_w, conv_b, dt_proj_w, dt_proj_b, A_log, Dvec, ln_w, ln_b};
        bf16* dsts[8] = {c_convw, c_convb, c_dtw, c_dtb, c_Alog, c_D, c_lnw, c_lnb};
        int ns[8] = {D_INNER * 4, D_INNER, D_INNER * DT_RANK, D_INNER,
                     D_INNER * D_STATE, D_INNER, D_MODEL, D_MODEL};
        int acc = 0;
        for (int i = 0; i < 8; i++) {
            b.src[i] = srcs[i]; b.dst[i] = dsts[i]; b.n[i] = ns[i];
            b.blockStart[i] = acc; acc += (ns[i] + 255) / 256;
        }
        b.blockStart[8] = acc; b.count = 8;
        convert_batch<<<dim3(acc), blk, 0, stream>>>(b, flag);
    }

    cvt(x, c_x, NROWS * D_MODEL);
    cvt(in_proj_w, c_wip, 2 * D_INNER * D_MODEL);

    // 1. in_proj: 256x256 kernel, N=4096, split store u | z
    gemm256<2><<<dim3(16 * 64), dim3(512), 0, stream>>>(
        c_x, D_MODEL, c_wip, D_MODEL, D_MODEL, nullptr,
        u, zbuf, D_INNER, /*NBX=*/16, /*Nsplit=*/D_INNER);

    // 2. conv + SiLU -> u_c (bufC copies die here)
    conv_silu<<<dim3((NROWS * D_INNER) / 256), blk, 0, stream>>>(u, u_c, c_convw, c_convb);

    // 3. x_proj (N=96): split-K x4 — grid (4,128) = 512 blocks (full chip)
    //    each covering K=512, fp32 partials in d_out, then combine -> bf16.
    cvt(x_proj_w, c_xpw, 96 * D_INNER);
    gemm_async<3><<<dim3(4, NROWS / 128), blk, 0, stream>>>(
        u_c, D_INNER, c_xpw, D_INNER, D_INNER / 4, nullptr,
        (bf16*)Ptmp, nullptr, 96, 96, /*Mrows=*/NROWS);
    combine_splitk<<<dim3((NROWS * 96 + 255) / 256), blk, 0, stream>>>(
        Ptmp, x_dbl, NROWS * 96, NROWS * 96);

    // 4. dt_proj + softplus -> delta: 256² kernel, NT=1, softplus epilogue
    gemm256<1><<<dim3(8 * 64), dim3(512), 0, stream>>>(
        x_dbl, 96, c_dtw, DT_RANK, DT_RANK, c_dtb,
        delta, nullptr, D_INNER, /*NBX=*/8, /*Nsplit=*/0);

    // 5. chunked selective scan (3 phases), gate fused; in-place into u_c
    scan_p1<<<dim3(BB * NCHUNK * 8), blk, 0, stream>>>(
        delta, u_c, x_dbl, A_log, flag, Pbuf, Sbuf);
    scan_p2<<<dim3(BB * 16 * 2048 / 256), blk, 0, stream>>>(Pbuf, Sbuf);
    scan_p3<<<dim3(BB * NCHUNK * 8), blk, 0, stream>>>(
        delta, u_c, x_dbl, zbuf, A_log, flag, c_D, Pbuf, u_c);

    // 6. out_proj -> y_out in bufZ: 256x256 kernel
    cvt(out_proj_w, c_opw, D_MODEL * D_INNER);
    gemm256<0><<<dim3(4 * 64), dim3(512), 0, stream>>>(
        u_c, D_INNER, c_opw, D_INNER, D_INNER, nullptr,
        y_out, nullptr, D_MODEL, /*NBX=*/4, /*Nsplit=*/0);

    // 7. LayerNorm -> d_out
    out_ln<<<dim3(NROWS), blk, 0, stream>>>(y_out, c_lnw, c_lnb, d_out, flag);
}

// Round 10
// 763.239 us; speedup vs baseline: 1.4205x; 1.0737x over previous
//
#include <hip/hip_runtime.h>
#include <hip/hip_bf16.h>
#include <math.h>

#define D_MODEL 1024
#define D_INNER 2048
#define D_STATE 16
#define DT_RANK 64
#define BB 4
#define LL 4096
#define NROWS (BB * LL)   // 16384
#define NCHUNK 32
#define TCHUNK 128        // NCHUNK * TCHUNK == LL

typedef __hip_bfloat16 bf16;
typedef __attribute__((ext_vector_type(8))) short short8;   // MFMA A/B frag (8 bf16)
typedef __attribute__((ext_vector_type(4))) float floatx4;  // MFMA C/D frag

__device__ __forceinline__ float silu_f(float x) { return x / (1.f + __expf(-x)); }
__device__ __forceinline__ float softplus_f(float x) { return x > 20.f ? x : log1pf(__expf(x)); }
__device__ __forceinline__ float bf2f(bf16 v) { return __bfloat162float(v); }
__device__ __forceinline__ bf16 f2bf(float v) { return __float2bfloat16(v); }

// raw v_exp_f32 (2^x). Callers pre-fold the log2e factor into the operand.
__device__ __forceinline__ float exp2_raw(float x) {
    float r;
    asm("v_exp_f32 %0, %1" : "=v"(r) : "v"(x));
    return r;
}

// async 16B global -> LDS copy (gfx950 global_load_lds_dwordx4).
// HW semantics: LDS dest = wave-uniform base + lane*16 [m97/m104].
__device__ __forceinline__ void gl2lds16(const bf16* g, short* lds) {
    __builtin_amdgcn_global_load_lds(
        (const __attribute__((address_space(1))) void*)g,
        (__attribute__((address_space(3))) void*)lds, 16, 0, 0);
}

// decode 8 consecutive bf16 (16-byte aligned) to fp32
__device__ __forceinline__ void load8_bf16(const bf16* p, float* f) {
    uint4 raw = *(const uint4*)p;
    unsigned int w0 = raw.x, w1 = raw.y, w2 = raw.z, w3 = raw.w;
    f[0] = __uint_as_float((w0 & 0xffffu) << 16);
    f[1] = __uint_as_float(w0 & 0xffff0000u);
    f[2] = __uint_as_float((w1 & 0xffffu) << 16);
    f[3] = __uint_as_float(w1 & 0xffff0000u);
    f[4] = __uint_as_float((w2 & 0xffffu) << 16);
    f[5] = __uint_as_float(w2 & 0xffff0000u);
    f[6] = __uint_as_float((w3 & 0xffffu) << 16);
    f[7] = __uint_as_float(w3 & 0xffff0000u);
}

// ---------------------------------------------------------------------------
// Input dtype detection (1 = fp32 inputs, 0 = bf16 inputs).
// ---------------------------------------------------------------------------
__global__ void detect_dtype(const void* xsrc, int* flag) {
    const unsigned short* p = (const unsigned short*)xsrc;
    int tid = threadIdx.x;
    int bad = 0;
    for (int i = tid; i < 2048; i += 256) {
        float v = __uint_as_float(((unsigned int)p[i]) << 16);
        if (!isfinite(v) || fabsf(v) > 1e6f) bad = 1;
    }
    __shared__ int sbad;
    if (tid == 0) sbad = 0;
    __syncthreads();
    if (bad) atomicOr(&sbad, 1);
    __syncthreads();
    if (tid == 0) *flag = sbad;
}

__global__ __launch_bounds__(256) void convert_to_bf16(
    const void* __restrict__ src, bf16* __restrict__ dst, int n,
    const int* __restrict__ flag)
{
    int i = blockIdx.x * 256 + threadIdx.x;
    if (i >= n) return;
    if (*flag)
        dst[i] = f2bf(((const float*)src)[i]);
    else
        dst[i] = ((const bf16*)src)[i];
}

// batch of small conversions in a single dispatch (saves ~7 launches)
struct CvtBatch {
    const void* src[8];
    bf16* dst[8];
    int n[8];
    int blockStart[9];   // prefix of ceil(n/256)
    int count;
};
__global__ __launch_bounds__(256) void convert_batch(CvtBatch b, const int* __restrict__ flag) {
    int bi = blockIdx.x;
    int seg = 0;
    while (seg + 1 < b.count && bi >= b.blockStart[seg + 1]) seg++;
    int i = (bi - b.blockStart[seg]) * 256 + threadIdx.x;
    if (i >= b.n[seg]) return;
    if (*flag)
        b.dst[seg][i] = f2bf(((const float*)b.src[seg])[i]);
    else
        b.dst[seg][i] = ((const bf16*)b.src[seg])[i];
}

// combine 4 split-K fp32 partials -> bf16 (coalesced: 1 elem/thread)
__global__ __launch_bounds__(256) void combine_splitk(
    const float* __restrict__ p, bf16* __restrict__ out, int n, int stride)
{
    int i = blockIdx.x * 256 + threadIdx.x;
    if (i >= n) return;
    float v = (p[i] + p[i + (size_t)stride]) +
              (p[i + 2 * (size_t)stride] + p[i + 3 * (size_t)stride]);
    out[i] = f2bf(v);
}

// ---------------------------------------------------------------------------
// Legacy 128x128 async-staged MFMA GEMM (m97 structure).
// EPI: 0 plain, 1 softplus+bias, 2 split store, 3 split-K fp32 partials
// (EPI=3: blockIdx.x = K-slice; partials at (float*)C + (slice*Mrows+row)*ldc.)
// ---------------------------------------------------------------------------
template <int EPI>
__global__ __launch_bounds__(256) void gemm_async(
    const bf16* __restrict__ A, int lda,
    const bf16* __restrict__ W, int ldw, int K,
    const bf16* __restrict__ bias,
    bf16* __restrict__ C, bf16* __restrict__ C2, int ldc,
    int N, int Nsplit)
{
    __shared__ short As[128 * 32];   // [m][k], 8 KB
    __shared__ short Bs[128 * 32];   // [n][k], 8 KB

    const int tid = threadIdx.x;
    const int m0 = blockIdx.y * 128;
    const int n0 = (EPI == 3) ? 0 : blockIdx.x * 128;
    const int ks = (EPI == 3) ? (int)blockIdx.x * K : 0;   // K-slice offset
    const int wid = tid >> 6;
    const int lane = tid & 63;
    const int wm = wid & 1;
    const int wn = wid >> 1;
    const int lm = lane & 15;
    const int quad = lane >> 4;

    floatx4 acc[4][4];
#pragma unroll
    for (int i = 0; i < 4; i++)
#pragma unroll
        for (int j = 0; j < 4; j++) acc[i][j] = (floatx4){0.f, 0.f, 0.f, 0.f};

    for (int k0 = 0; k0 < K; k0 += 32) {
#pragma unroll
        for (int j = 0; j < 2; j++) {
            int cbase = (wid * 2 + j) * 64;       // wave-uniform
            int c = cbase + lane;
            int row = c >> 2, seg = c & 3;
            gl2lds16(A + (size_t)(m0 + row) * lda + ks + k0 + seg * 8, &As[cbase * 8]);
        }
#pragma unroll
        for (int j = 0; j < 2; j++) {
            int cbase = (wid * 2 + j) * 64;
            int c = cbase + lane;
            int row = c >> 2, seg = c & 3;
            int wrow = n0 + row; if (wrow >= N) wrow = N - 1;
            gl2lds16(W + (size_t)wrow * ldw + ks + k0 + seg * 8, &Bs[cbase * 8]);
        }
        __syncthreads();

        short8 af[4], bfr[4];
#pragma unroll
        for (int mt = 0; mt < 4; mt++)
            af[mt] = *(const short8*)&As[(wm * 64 + mt * 16 + lm) * 32 + quad * 8];
#pragma unroll
        for (int nt = 0; nt < 4; nt++)
            bfr[nt] = *(const short8*)&Bs[(wn * 64 + nt * 16 + lm) * 32 + quad * 8];
        __syncthreads();

#pragma unroll
        for (int mt = 0; mt < 4; mt++)
#pragma unroll
            for (int nt = 0; nt < 4; nt++)
                acc[mt][nt] = __builtin_amdgcn_mfma_f32_16x16x32_bf16(
                    af[mt], bfr[nt], acc[mt][nt], 0, 0, 0);
    }

#pragma unroll
    for (int mt = 0; mt < 4; mt++) {
#pragma unroll
        for (int nt = 0; nt < 4; nt++) {
            int col = n0 + wn * 64 + nt * 16 + lm;
            if (col >= N) continue;
            int rbase = m0 + wm * 64 + mt * 16 + quad * 4;
#pragma unroll
            for (int r = 0; r < 4; r++) {
                float v = acc[mt][nt][r];
                if (EPI == 3) {
                    ((float*)C)[((size_t)blockIdx.x * Nsplit + rbase + r) * ldc + col] = v;
                } else if (EPI == 1) {
                    C[(size_t)(rbase + r) * ldc + col] = f2bf(softplus_f(v + bf2f(bias[col])));
                } else if (EPI == 2) {
                    if (col < Nsplit)
                        C[(size_t)(rbase + r) * ldc + col] = f2bf(v);
                    else
                        C2[(size_t)(rbase + r) * ldc + (col - Nsplit)] = f2bf(v);
                } else {
                    C[(size_t)(rbase + r) * ldc + col] = f2bf(v);
                }
            }
        }
    }
}

// ---------------------------------------------------------------------------
// 256x256 MFMA GEMM.  R10: rotate-prefetch schedule.
// C[M,N] = A[M,K] @ W[N,K]^T.  M%256==0, N%256==0, K%64==0, K>=64.
// EPI: 0 plain, 1 softplus+bias, 2 split.  R7 XCD swizzle (proven).
//
// R10 theory: per-CU per-tile LDS = 24 reads x 8 waves x ~12cyc ~= 2300 cyc,
// MFMA ~= 620, observed ~5400 -> the gap is tile-entry read serialization
// (all 24 reads sit between barrier#2 and C0 with no MFMA to hide under).
// Fix with ZERO extra VGPRs (128 arch + 128 acc = 256/wave is the cap):
// af0/bv0 double as the prefetch registers.  Cluster order:
//   top:   READ bv1,af1 (12)          [drains under C0/C1]
//          C0=(af0,bv0)  C1=(af0,bv1)
//   #1 ->  stages(t+2);  C3=(af1,bv0)   [af0,bv0 now dead]
//          vmcnt(4); lgkmcnt(0); barrier #2
//          READ af0,bv0 <- buf(t+1)   [prefetch, drains under C2 + next top]
//          C2=(af1,bv1)
// Safety: lgkmcnt(0) before #2 pins all tile-t reads complete before any
// wave's next-iter stages overwrite their source regions; prefetch sources
// (A-half0/B-half0 of buf(t+1)) proven complete by vmcnt(4)+#2; WAR register
// dataflow on af0/bv0 keeps C0/C1/C3 correct under any compiler reordering.
// ---------------------------------------------------------------------------
template <int EPI>
__global__ __launch_bounds__(512, 2) void gemm256(
    const bf16* __restrict__ A, int lda,
    const bf16* __restrict__ W, int ldw, int K,
    const bf16* __restrict__ bias,
    bf16* __restrict__ C, bf16* __restrict__ C2, int ldc,
    int NBX, int Nsplit)
{
    __shared__ short lds[65536];   // 128 KB: [buf][A 16384 | B 16384] shorts

    const int tid = threadIdx.x;
    const int wid = tid >> 6;
    const int lane = tid & 63;
    const int lm = lane & 15;
    const int quad = lane >> 4;
    const int wm = wid >> 2;      // 0..1
    const int wn = wid & 3;       // 0..3

    // XCD-aware bijective swizzle (caller guarantees nwg % 8 == 0) — R7 form
    const int nwg = (int)gridDim.x;
    const int wg = (int)blockIdx.x;
    const int swz = (wg & 7) * (nwg >> 3) + (wg >> 3);
    const int by = swz / NBX;
    const int bx = swz - by * NBX;
    const int m0 = by * 256;
    const int n0 = bx * 256;

    const int NT = K >> 6;

    floatx4 acc[2][4][2][2];
#pragma unroll
    for (int a = 0; a < 2; a++)
#pragma unroll
        for (int b = 0; b < 4; b++)
#pragma unroll
            for (int c = 0; c < 2; c++)
#pragma unroll
                for (int d = 0; d < 2; d++) acc[a][b][c][d] = (floatx4){0.f, 0.f, 0.f, 0.f};

    // stage one 16 KB half of the A (resp. B) tile of K-step t_ into buffer bsel.
    auto stageA = [&](int bsel, int t_, int half) {
        short* base = &lds[bsel * 32768];
        const bf16* g = A + (size_t)m0 * lda + t_ * 64;
#pragma unroll
        for (int part = 0; part < 2; part++) {
            int cbase = half * 512 + part * 1024 + wid * 64;   // wave-uniform
            int c = cbase + lane;
            int row = c >> 3;
            int gs = (c & 7) ^ (row & 7);                      // inverse swizzle on source
            gl2lds16(g + (size_t)row * lda + gs * 8, base + cbase * 8);
        }
    };
    auto stageB = [&](int bsel, int t_, int half) {
        short* base = &lds[bsel * 32768 + 16384];
        const bf16* g = W + (size_t)n0 * ldw + t_ * 64;
#pragma unroll
        for (int part = 0; part < 2; part++) {
            int cbase = half * 1024 + part * 512 + wid * 64;
            int c = cbase + lane;
            int row = c >> 3;
            int gs = (c & 7) ^ (row & 7);
            gl2lds16(g + (size_t)row * ldw + gs * 8, base + cbase * 8);
        }
    };

    // ---- prologue
    stageA(0, 0, 0); stageA(0, 0, 1); stageB(0, 0, 0); stageB(0, 0, 1);
    if (NT > 1) { stageA(1, 1, 0); stageB(1, 1, 1); }
    if (NT > 1) asm volatile("s_waitcnt vmcnt(4)" ::: "memory");
    else        asm volatile("s_waitcnt vmcnt(0)" ::: "memory");
    __builtin_amdgcn_s_barrier();

#define READ_A(BASE, DST, MH)                                                   \
    _Pragma("unroll")                                                           \
    for (int mt = 0; mt < 4; mt++) {                                            \
        int r = wm * 128 + (MH) * 64 + mt * 16 + lm;                            \
        _Pragma("unroll")                                                       \
        for (int kk = 0; kk < 2; kk++)                                          \
            DST[mt][kk] = *(const short8*)&(BASE)[r * 64 + (((kk * 4 + quad) ^ (r & 7)) * 8)]; \
    }
#define READ_B(BASE, DST, NH)                                                   \
    _Pragma("unroll")                                                           \
    for (int nf = 0; nf < 2; nf++) {                                            \
        int r = (NH) * 128 + wn * 32 + nf * 16 + lm;                            \
        _Pragma("unroll")                                                       \
        for (int kk = 0; kk < 2; kk++)                                          \
            DST[nf][kk] = *(const short8*)&(BASE)[r * 64 + (((kk * 4 + quad) ^ (r & 7)) * 8)]; \
    }
#define MFMA16(AF, BV, MH, NH)                                                  \
    __builtin_amdgcn_s_setprio(1);                                              \
    _Pragma("unroll")                                                           \
    for (int mt = 0; mt < 4; mt++)                                              \
        _Pragma("unroll")                                                       \
        for (int nf = 0; nf < 2; nf++)                                          \
            _Pragma("unroll")                                                   \
            for (int kk = 0; kk < 2; kk++)                                      \
                acc[MH][mt][NH][nf] = __builtin_amdgcn_mfma_f32_16x16x32_bf16(  \
                    AF[mt][kk], BV[nf][kk], acc[MH][mt][NH][nf], 0, 0, 0);      \
    __builtin_amdgcn_s_setprio(0);

    short8 af0[4][2], af1[4][2], bv0[2][2], bv1[2][2];
    // prologue prefetch: tile0 af0/bv0
    {
        short* An_ = &lds[0];
        short* Bn_ = &lds[16384];
        READ_A(An_, af0, 0)
        READ_B(Bn_, bv0, 0)
    }

    for (int t = 0; t < NT; t++) {
        const int buf = t & 1;
        const int bufn = buf ^ 1;
        short* As_ = &lds[buf * 32768];
        short* Bs_ = &lds[buf * 32768 + 16384];

        READ_B(Bs_, bv1, 1)
        READ_A(As_, af1, 1)

        if (t + 1 < NT) { stageA(bufn, t + 1, 1); stageB(bufn, t + 1, 0); }

        MFMA16(af0, bv0, 0, 0)      // C0 — waits only on prefetched af0/bv0
        MFMA16(af0, bv1, 0, 1)      // C1 — bv1 drained under C0

        __builtin_amdgcn_s_barrier();   // #1: af0-region & bv1-region consumed

        if (t + 2 < NT) { stageA(buf, t + 2, 0); stageB(buf, t + 2, 1); }

        MFMA16(af1, bv0, 1, 0)      // C3 — af0/bv0 registers now dead

        if (t + 2 < NT)      { asm volatile("s_waitcnt vmcnt(4)" ::: "memory"); }
        else if (t + 1 < NT) { asm volatile("s_waitcnt vmcnt(0)" ::: "memory"); }
        asm volatile("s_waitcnt lgkmcnt(0)" ::: "memory");   // pin tile-t reads
        __builtin_amdgcn_s_barrier();   // #2: buf(t+1) proven complete

        if (t + 1 < NT) {
            short* An_ = &lds[bufn * 32768];
            short* Bn_ = &lds[bufn * 32768 + 16384];
            READ_A(An_, af0, 0)     // prefetch tile t+1 into rotated regs
            READ_B(Bn_, bv0, 0)
        }

        MFMA16(af1, bv1, 1, 1)      // C2 — regs only; prefetch drains under it
    }
#undef READ_A
#undef READ_B
#undef MFMA16

    // epilogue: C/D layout col = lane&15, row = quad*4 + r  [m89/m91]
#pragma unroll
    for (int mh = 0; mh < 2; mh++)
#pragma unroll
        for (int mt = 0; mt < 4; mt++)
#pragma unroll
            for (int nh = 0; nh < 2; nh++)
#pragma unroll
                for (int nf = 0; nf < 2; nf++) {
                    int col = n0 + nh * 128 + wn * 32 + nf * 16 + lm;
                    int rbase = m0 + wm * 128 + mh * 64 + mt * 16 + quad * 4;
#pragma unroll
                    for (int r = 0; r < 4; r++) {
                        float v = acc[mh][mt][nh][nf][r];
                        if (EPI == 1) v = softplus_f(v + bf2f(bias[col]));
                        if (EPI == 2) {
                            if (col < Nsplit)
                                C[(size_t)(rbase + r) * ldc + col] = f2bf(v);
                            else
                                C2[(size_t)(rbase + r) * ldc + (col - Nsplit)] = f2bf(v);
                        } else {
                            C[(size_t)(rbase + r) * ldc + col] = f2bf(v);
                        }
                    }
                }
}

// ---------------------------------------------------------------------------
// Causal depthwise conv1d (width 4) + bias + SiLU.  R10: x8 vectorized
// (short8 loads/stores, 8 channels/thread — G13; was scalar bf16).
// ---------------------------------------------------------------------------
__global__ __launch_bounds__(256) void conv_silu(
    const bf16* __restrict__ u,
    bf16* __restrict__ u_c,
    const bf16* __restrict__ w,
    const bf16* __restrict__ bias)
{
    int gid = blockIdx.x * 256 + threadIdx.x;
    if (gid >= NROWS * (D_INNER / 8)) return;
    int dg = gid & (D_INNER / 8 - 1);
    int row = gid >> 8;
    int l = row & (LL - 1);
    int d0 = dg * 8;

    float wv[32];   // taps for 8 channels: wv[j*4+t]
    load8_bf16(w + d0 * 4, wv);
    load8_bf16(w + d0 * 4 + 8, wv + 8);
    load8_bf16(w + d0 * 4 + 16, wv + 16);
    load8_bf16(w + d0 * 4 + 24, wv + 24);
    float acc[8];
    load8_bf16(bias + d0, acc);

#pragma unroll
    for (int t = 0; t < 4; t++) {
        int ls = l - 3 + t;
        if (ls >= 0) {
            float uv[8];
            load8_bf16(u + (size_t)(row - 3 + t) * D_INNER + d0, uv);
#pragma unroll
            for (int j = 0; j < 8; j++)
                acc[j] = fmaf(wv[j * 4 + t], uv[j], acc[j]);
        }
    }

    union { short8 v; unsigned short s[8]; } o;
#pragma unroll
    for (int j = 0; j < 8; j++)
        o.s[j] = __bfloat16_as_ushort(f2bf(silu_f(acc[j])));
    *(short8*)&u_c[(size_t)row * D_INNER + d0] = o.v;
}

// ---------------------------------------------------------------------------
// Chunked selective scan (3 phases).  R6: A_log read in original precision
// so the POW16 structure check passes (bf16 copy failed the 1e-4 check).
// ---------------------------------------------------------------------------

// dA[0..15] = q^(n+1), 15 muls, depth ~4
#define POW16(DA, Q) do {                                                     \
    float q1 = (Q);                                                           \
    float q2 = q1 * q1;                                                       \
    float q3 = q2 * q1;                                                       \
    float q4 = q2 * q2;                                                       \
    float q8 = q4 * q4;                                                       \
    DA[0] = q1;       DA[1] = q2;       DA[2] = q3;       DA[3] = q4;         \
    DA[4] = q4 * q1;  DA[5] = q4 * q2;  DA[6] = q4 * q3;  DA[7] = q8;         \
    DA[8] = q8 * q1;  DA[9] = q8 * q2;  DA[10] = q8 * q3; DA[11] = q8 * q4;   \
    DA[12] = q8 * DA[4]; DA[13] = q8 * DA[5]; DA[14] = q8 * DA[6];            \
    DA[15] = q8 * q8;                                                         \
} while (0)

__device__ __forceinline__ bool ac_structured(const float* Ac) {
    float a0 = Ac[0];
    bool ok = true;
#pragma unroll
    for (int n = 1; n < 16; n++) {
        float want = (float)(n + 1) * a0;
        ok = ok && (fabsf(Ac[n] - want) <= 1e-4f * fabsf(want) + 1e-12f);
    }
    return ok;
}

// load A_log row d (16 values) in original precision, produce exp2-domain Ac
__device__ __forceinline__ void load_Ac(const void* A_log_raw, int fp32, int d, float* Ac) {
    float f[16];
    if (fp32) {
        const float* ap = (const float*)A_log_raw + (size_t)d * 16;
#pragma unroll
        for (int n = 0; n < 16; n++) f[n] = ap[n];
    } else {
        const bf16* ap = (const bf16*)A_log_raw + (size_t)d * 16;
        load8_bf16(ap, f);
        load8_bf16(ap + 8, f + 8);
    }
#pragma unroll
    for (int n = 0; n < 16; n++) Ac[n] = -__expf(f[n]) * 1.4426950408889634f;
}

__global__ __launch_bounds__(256) void scan_p1(
    const bf16* __restrict__ delta,
    const bf16* __restrict__ uc,
    const bf16* __restrict__ x_dbl,
    const void* __restrict__ A_log_raw,
    const int* __restrict__ flag,
    float* __restrict__ Pbuf, float* __restrict__ Sbuf)
{
    __shared__ float Bsh[TCHUNK * 16];
    const int tid = threadIdx.x;
    const int bx = blockIdx.x;
    const int dt = bx & 7;
    const int c = (bx >> 3) & (NCHUNK - 1);
    const int b = bx / (NCHUNK * 8);
    const int d = dt * 256 + tid;
    const int rowb = b * LL + c * TCHUNK;

    if (tid < TCHUNK) {
        float f[16];
        const bf16* p = x_dbl + (size_t)(rowb + tid) * 96 + DT_RANK;
        load8_bf16(p, f);
        load8_bf16(p + 8, f + 8);
#pragma unroll
        for (int n = 0; n < 16; n++) Bsh[tid * 16 + n] = f[n];
    }

    float Ac[16];   // -exp(A_log) * log2e  (exp2-domain)
    load_Ac(A_log_raw, *flag, d, Ac);
    const float a0 = Ac[0];
    const bool fast = ac_structured(Ac);
    __syncthreads();

    float h[16];
    float sdl = 0.f;   // sum of dl over chunk -> Pp via exp2(Ac*sdl)
#pragma unroll
    for (int n = 0; n < 16; n++) h[n] = 0.f;

    size_t g = (size_t)rowb * 2048 + d;
    float dl = bf2f(delta[g]);
    float uv = bf2f(uc[g]);

#define P1_BODY(DA_STMT)                                                      \
    for (int t = 0; t < TCHUNK; t++) {                                        \
        float dl_n = 0.f, uv_n = 0.f;                                         \
        if (t + 1 < TCHUNK) {                                                 \
            g += 2048;                                                        \
            dl_n = bf2f(delta[g]);                                            \
            uv_n = bf2f(uc[g]);                                               \
        }                                                                     \
        float dlu = dl * uv;                                                  \
        float dAv[16];                                                        \
        DA_STMT;                                                              \
        float bb[16];                                                         \
        {                                                                     \
            const float4* Bv = (const float4*)&Bsh[t * 16];                   \
            *(float4*)&bb[0] = Bv[0]; *(float4*)&bb[4] = Bv[1];               \
            *(float4*)&bb[8] = Bv[2]; *(float4*)&bb[12] = Bv[3];              \
        }                                                                     \
        _Pragma("unroll")                                                     \
        for (int n = 0; n < 16; n++)                                          \
            h[n] = fmaf(dAv[n], h[n], dlu * bb[n]);                           \
        sdl += dl;                                                            \
        dl = dl_n; uv = uv_n;                                                 \
    }

    if (fast) {
        P1_BODY(POW16(dAv, exp2_raw(dl * a0)))
    } else {
        P1_BODY({ _Pragma("unroll") for (int n = 0; n < 16; n++) dAv[n] = exp2_raw(dl * Ac[n]); })
    }
#undef P1_BODY

    size_t base = (((size_t)b * NCHUNK + c) * 16) * 2048 + d;
#pragma unroll
    for (int n = 0; n < 16; n++) {
        Pbuf[base + (size_t)n * 2048] = exp2_raw(Ac[n] * sdl);
        Sbuf[base + (size_t)n * 2048] = h[n];
    }
}

__global__ __launch_bounds__(256) void scan_p2(
    float* __restrict__ Pbuf, const float* __restrict__ Sbuf)
{
    int gid = blockIdx.x * 256 + threadIdx.x;
    int b = gid >> 15;
    int n = (gid >> 11) & 15;
    int d = gid & 2047;
    float hinit = 0.f;
    for (int c = 0; c < NCHUNK; c++) {
        size_t idx = (((size_t)b * NCHUNK + c) * 16 + n) * 2048 + d;
        float p = Pbuf[idx];
        float s = Sbuf[idx];
        Pbuf[idx] = hinit;
        hinit = fmaf(p, hinit, s);
    }
}

__global__ __launch_bounds__(256) void scan_p3(
    const bf16* __restrict__ delta,
    const bf16* uc,
    const bf16* __restrict__ x_dbl,
    const bf16* __restrict__ z,
    const void* __restrict__ A_log_raw,
    const int* __restrict__ flag,
    const bf16* __restrict__ Dvec,
    const float* __restrict__ Hinit,
    bf16* yg)
{
    __shared__ float Bsh[TCHUNK * 16];
    __shared__ float Csh[TCHUNK * 16];
    const int tid = threadIdx.x;
    const int bx = blockIdx.x;
    const int dt = bx & 7;
    const int c = (bx >> 3) & (NCHUNK - 1);
    const int b = bx / (NCHUNK * 8);
    const int d = dt * 256 + tid;
    const int rowb = b * LL + c * TCHUNK;

    if (tid < TCHUNK) {
        float f[16];
        const bf16* p = x_dbl + (size_t)(rowb + tid) * 96 + DT_RANK;
        load8_bf16(p, f);
        load8_bf16(p + 8, f + 8);
#pragma unroll
        for (int n = 0; n < 16; n++) Bsh[tid * 16 + n] = f[n];
        load8_bf16(p + 16, f);
        load8_bf16(p + 24, f + 8);
#pragma unroll
        for (int n = 0; n < 16; n++) Csh[tid * 16 + n] = f[n];
    }

    float Ac[16];   // -exp(A_log) * log2e  (exp2-domain)
    load_Ac(A_log_raw, *flag, d, Ac);
    const float a0 = Ac[0];
    const bool fast = ac_structured(Ac);
    const float Dv = bf2f(Dvec[d]);
    __syncthreads();

    float h[16];
    size_t base = (((size_t)b * NCHUNK + c) * 16) * 2048 + d;
#pragma unroll
    for (int n = 0; n < 16; n++) h[n] = Hinit[base + (size_t)n * 2048];

    size_t g = (size_t)rowb * 2048 + d;
    float dl = bf2f(delta[g]);
    float uv = bf2f(uc[g]);
    float zv = bf2f(z[g]);
    size_t gw = g;

#define P3_BODY(DA_STMT)                                                      \
    for (int t = 0; t < TCHUNK; t++) {                                        \
        float dl_n = 0.f, uv_n = 0.f, zv_n = 0.f;                             \
        if (t + 1 < TCHUNK) {                                                 \
            g += 2048;                                                        \
            dl_n = bf2f(delta[g]);                                            \
            uv_n = bf2f(uc[g]);                                               \
            zv_n = bf2f(z[g]);                                                \
        }                                                                     \
        float dlu = dl * uv;                                                  \
        float dAv[16];                                                        \
        DA_STMT;                                                              \
        float bb[16], cc[16];                                                 \
        {                                                                     \
            const float4* Bv = (const float4*)&Bsh[t * 16];                   \
            const float4* Cv = (const float4*)&Csh[t * 16];                   \
            *(float4*)&bb[0] = Bv[0]; *(float4*)&bb[4] = Bv[1];               \
            *(float4*)&bb[8] = Bv[2]; *(float4*)&bb[12] = Bv[3];              \
            *(float4*)&cc[0] = Cv[0]; *(float4*)&cc[4] = Cv[1];               \
            *(float4*)&cc[8] = Cv[2]; *(float4*)&cc[12] = Cv[3];              \
        }                                                                     \
        float yp0 = 0.f, yp1 = 0.f, yp2 = 0.f, yp3 = 0.f;                     \
        _Pragma("unroll")                                                     \
        for (int n = 0; n < 16; n += 4) {                                     \
            h[n]     = fmaf(dAv[n],     h[n],     dlu * bb[n]);               \
            h[n + 1] = fmaf(dAv[n + 1], h[n + 1], dlu * bb[n + 1]);           \
            h[n + 2] = fmaf(dAv[n + 2], h[n + 2], dlu * bb[n + 2]);           \
            h[n + 3] = fmaf(dAv[n + 3], h[n + 3], dlu * bb[n + 3]);           \
            yp0 = fmaf(h[n],     cc[n],     yp0);                             \
            yp1 = fmaf(h[n + 1], cc[n + 1], yp1);                             \
            yp2 = fmaf(h[n + 2], cc[n + 2], yp2);                             \
            yp3 = fmaf(h[n + 3], cc[n + 3], yp3);                             \
        }                                                                     \
        float y = (yp0 + yp1) + (yp2 + yp3);                                  \
        y = fmaf(uv, Dv, y);                                                  \
        yg[gw] = f2bf(y * silu_f(zv));                                        \
        gw += 2048;                                                           \
        dl = dl_n; uv = uv_n; zv = zv_n;                                      \
    }

    if (fast) {
        P3_BODY(POW16(dAv, exp2_raw(dl * a0)))
    } else {
        P3_BODY({ _Pragma("unroll") for (int n = 0; n < 16; n++) dAv[n] = exp2_raw(dl * Ac[n]); })
    }
#undef P3_BODY
}

// ---------------------------------------------------------------------------
// LayerNorm over last dim (1024). Output dtype per flag (1=fp32, 0=bf16).
// ---------------------------------------------------------------------------
__global__ __launch_bounds__(256) void out_ln(
    const bf16* __restrict__ o,
    const bf16* __restrict__ lw,
    const bf16* __restrict__ lb,
    void* __restrict__ outv,
    const int* __restrict__ flag)
{
    __shared__ float sm[4];
    const int row = blockIdx.x;
    const int tid = threadIdx.x;
    const int lane = tid & 63;
    const int wid = tid >> 6;
    const int c = tid * 4;

    const bf16* rp = o + (size_t)row * 1024 + c;
    float v0 = bf2f(rp[0]), v1 = bf2f(rp[1]), v2 = bf2f(rp[2]), v3 = bf2f(rp[3]);

    float s = v0 + v1 + v2 + v3;
#pragma unroll
    for (int off = 1; off < 64; off <<= 1) s += __shfl_xor(s, off, 64);
    if (lane == 0) sm[wid] = s;
    __syncthreads();
    float mu = (sm[0] + sm[1] + sm[2] + sm[3]) * (1.f / 1024.f);
    __syncthreads();

    float dx0 = v0 - mu, dx1 = v1 - mu, dx2 = v2 - mu, dx3 = v3 - mu;
    float q = dx0 * dx0 + dx1 * dx1 + dx2 * dx2 + dx3 * dx3;
#pragma unroll
    for (int off = 1; off < 64; off <<= 1) q += __shfl_xor(q, off, 64);
    if (lane == 0) sm[wid] = q;
    __syncthreads();
    float var = (sm[0] + sm[1] + sm[2] + sm[3]) * (1.f / 1024.f);
    float inv = rsqrtf(var + 1e-5f);

    float w0 = bf2f(lw[c]), w1 = bf2f(lw[c + 1]), w2 = bf2f(lw[c + 2]), w3 = bf2f(lw[c + 3]);
    float b0 = bf2f(lb[c]), b1 = bf2f(lb[c + 1]), b2 = bf2f(lb[c + 2]), b3 = bf2f(lb[c + 3]);
    float r0 = dx0 * inv * w0 + b0;
    float r1 = dx1 * inv * w1 + b1;
    float r2 = dx2 * inv * w2 + b2;
    float r3 = dx3 * inv * w3 + b3;

    if (*flag) {
        float4* wp = (float4*)((float*)outv + (size_t)row * 1024 + c);
        *wp = make_float4(r0, r1, r2, r3);
    } else {
        bf16* wp = (bf16*)outv + (size_t)row * 1024 + c;
        wp[0] = f2bf(r0); wp[1] = f2bf(r1); wp[2] = f2bf(r2); wp[3] = f2bf(r3);
    }
}

// ---------------------------------------------------------------------------
extern "C" void kernel_launch(void* const* d_in, const int* in_sizes, int n_in,
                              void* d_out, int out_size, void* d_ws, size_t ws_size,
                              hipStream_t stream)
{
    const void* x          = d_in[0];
    const void* in_proj_w  = d_in[1];
    const void* conv_w     = d_in[2];
    const void* conv_b     = d_in[3];
    const void* x_proj_w   = d_in[4];
    const void* dt_proj_w  = d_in[5];
    const void* dt_proj_b  = d_in[6];
    const void* A_log      = d_in[7];
    const void* Dvec       = d_in[8];
    const void* out_proj_w = d_in[9];
    const void* ln_w       = d_in[10];
    const void* ln_b       = d_in[11];

    size_t nBig = (size_t)NROWS * D_INNER;
    size_t xdblN = (size_t)NROWS * 96;
    size_t need = (3 * nBig + xdblN + 196608) * 2;
    if (ws_size < need) {
        hipMemsetAsync(d_out, 0, (size_t)out_size * 2, stream);
        return;
    }

    bf16* bufA = (bf16*)d_ws;       // u -> x_proj_w copy -> delta -> out_proj_w copy
    bf16* bufZ = bufA + nBig;       // z -> y_out
    bf16* bufC = bufZ + nBig;       // x+in_proj_w copies -> u_c / y_gated
    bf16* bufX = bufC + nBig;       // x_dbl
    bf16* bufS = bufX + xdblN;      // flag + small consts

    int*  flag    = (int*)bufS;
    bf16* c_convw = bufS + 16;
    bf16* c_convb = c_convw + 8192;
    bf16* c_dtw   = c_convb + 2048;
    bf16* c_dtb   = c_dtw + 131072;
    bf16* c_Alog  = c_dtb + 2048;
    bf16* c_D     = c_Alog + 32768;
    bf16* c_lnw   = c_D + 2048;
    bf16* c_lnb   = c_lnw + 1024;

    bf16* c_x    = bufC;
    bf16* c_wip  = bufC + (size_t)NROWS * 1024;
    bf16* c_xpw  = bufA;
    bf16* c_opw  = bufA;
    bf16* u      = bufA;
    bf16* delta  = bufA;
    bf16* zbuf   = bufZ;
    bf16* y_out  = bufZ;
    bf16* u_c    = bufC;
    bf16* x_dbl  = bufX;

    // d_out scratch timeline: [x_proj split-K partials 25.2MB] -> [scan P/S
    // 33.5MB] -> [LN output].  No temporal overlap.
    float* Ptmp = (float*)d_out;                      // 4 x 16384 x 96 fp32
    float* Pbuf = (float*)d_out;
    float* Sbuf = Pbuf + (size_t)BB * NCHUNK * 16 * 2048;

    dim3 blk(256);
    auto cvt = [&](const void* src, bf16* dst, int n) {
        convert_to_bf16<<<dim3((n + 255) / 256), blk, 0, stream>>>(src, dst, n, flag);
    };

    // 0. detect input dtype
    detect_dtype<<<dim3(1), blk, 0, stream>>>(x, flag);

    // small consts: one batched dispatch
    {
        CvtBatch b{};
        const void* srcs[8] = {conv_w, conv_b, dt_proj_w, dt_proj_b, A_log, Dvec, ln_w, ln_b};
        bf16* dsts[8] = {c_convw, c_convb, c_dtw, c_dtb, c_Alog, c_D, c_lnw, c_lnb};
        int ns[8] = {D_INNER * 4, D_INNER, D_INNER * DT_RANK, D_INNER,
                     D_INNER * D_STATE, D_INNER, D_MODEL, D_MODEL};
        int acc = 0;
        for (int i = 0; i < 8; i++) {
            b.src[i] = srcs[i]; b.dst[i] = dsts[i]; b.n[i] = ns[i];
            b.blockStart[i] = acc; acc += (ns[i] + 255) / 256;
        }
        b.blockStart[8] = acc; b.count = 8;
        convert_batch<<<dim3(acc), blk, 0, stream>>>(b, flag);
    }

    cvt(x, c_x, NROWS * D_MODEL);
    cvt(in_proj_w, c_wip, 2 * D_INNER * D_MODEL);

    // 1. in_proj: 256x256 kernel, N=4096, split store u | z
    gemm256<2><<<dim3(16 * 64), dim3(512), 0, stream>>>(
        c_x, D_MODEL, c_wip, D_MODEL, D_MODEL, nullptr,
        u, zbuf, D_INNER, /*NBX=*/16, /*Nsplit=*/D_INNER);

    // 2. conv + SiLU -> u_c (x8 vectorized)
    conv_silu<<<dim3(NROWS * (D_INNER / 8) / 256), blk, 0, stream>>>(u, u_c, c_convw, c_convb);

    // 3. x_proj (N=96): split-K x4 — grid (4,128) = 512 blocks (full chip)
    cvt(x_proj_w, c_xpw, 96 * D_INNER);
    gemm_async<3><<<dim3(4, NROWS / 128), blk, 0, stream>>>(
        u_c, D_INNER, c_xpw, D_INNER, D_INNER / 4, nullptr,
        (bf16*)Ptmp, nullptr, 96, 96, /*Mrows=*/NROWS);
    combine_splitk<<<dim3((NROWS * 96 + 255) / 256), blk, 0, stream>>>(
        Ptmp, x_dbl, NROWS * 96, NROWS * 96);

    // 4. dt_proj + softplus -> delta: 256² kernel, NT=1, softplus epilogue
    gemm256<1><<<dim3(8 * 64), dim3(512), 0, stream>>>(
        x_dbl, 96, c_dtw, DT_RANK, DT_RANK, c_dtb,
        delta, nullptr, D_INNER, /*NBX=*/8, /*Nsplit=*/0);

    // 5. chunked selective scan (3 phases), gate fused; in-place into u_c
    scan_p1<<<dim3(BB * NCHUNK * 8), blk, 0, stream>>>(
        delta, u_c, x_dbl, A_log, flag, Pbuf, Sbuf);
    scan_p2<<<dim3(BB * 16 * 2048 / 256), blk, 0, stream>>>(Pbuf, Sbuf);
    scan_p3<<<dim3(BB * NCHUNK * 8), blk, 0, stream>>>(
        delta, u_c, x_dbl, zbuf, A_log, flag, c_D, Pbuf, u_c);

    // 6. out_proj -> y_out in bufZ: 256x256 kernel
    cvt(out_proj_w, c_opw, D_MODEL * D_INNER);
    gemm256<0><<<dim3(4 * 64), dim3(512), 0, stream>>>(
        u_c, D_INNER, c_opw, D_INNER, D_INNER, nullptr,
        y_out, nullptr, D_MODEL, /*NBX=*/4, /*Nsplit=*/0);

    // 7. LayerNorm -> d_out
    out_ln<<<dim3(NROWS), blk, 0, stream>>>(y_out, c_lnw, c_lnb, d_out, flag);
}

// Round 11
// 644.372 us; speedup vs baseline: 1.6825x; 1.1845x over previous
//
#include <hip/hip_runtime.h>
#include <hip/hip_bf16.h>
#include <math.h>

#define D_MODEL 1024
#define D_INNER 2048
#define D_STATE 16
#define DT_RANK 64
#define BB 4
#define LL 4096
#define NROWS (BB * LL)   // 16384
#define NCHUNK 32
#define TCHUNK 128        // NCHUNK * TCHUNK == LL

typedef __hip_bfloat16 bf16;
typedef __attribute__((ext_vector_type(8))) short short8;   // MFMA A/B frag (8 bf16)
typedef __attribute__((ext_vector_type(4))) float floatx4;  // MFMA C/D frag

__device__ __forceinline__ float silu_f(float x) { return x / (1.f + __expf(-x)); }
__device__ __forceinline__ float bf2f(bf16 v) { return __bfloat162float(v); }
__device__ __forceinline__ bf16 f2bf(float v) { return __float2bfloat16(v); }

// R11: fast softplus.  The libm log1pf path compiled to ~260 VALU instrs per
// call (dt_proj epilogue = 82% VALUBusy, 136us).  Stable 2-transcendental
// form: softplus(x) = max(x,0) + ln2 * log2(1 + exp2(-|x|*log2e)).
// x->+inf: log2(1)=0 -> x;  x->-inf: max=0, term -> exp(x).  ~8 instrs.
__device__ __forceinline__ float softplus_f(float x) {
    float e, l;
    asm("v_exp_f32 %0, %1" : "=v"(e) : "v"(-fabsf(x) * 1.4426950408889634f));
    asm("v_log_f32 %0, %1" : "=v"(l) : "v"(1.f + e));
    return fmaxf(x, 0.f) + l * 0.6931471805599453f;
}

// raw v_exp_f32 (2^x). Callers pre-fold the log2e factor into the operand.
__device__ __forceinline__ float exp2_raw(float x) {
    float r;
    asm("v_exp_f32 %0, %1" : "=v"(r) : "v"(x));
    return r;
}

// async 16B global -> LDS copy (gfx950 global_load_lds_dwordx4).
// HW semantics: LDS dest = wave-uniform base + lane*16 [m97/m104].
__device__ __forceinline__ void gl2lds16(const bf16* g, short* lds) {
    __builtin_amdgcn_global_load_lds(
        (const __attribute__((address_space(1))) void*)g,
        (__attribute__((address_space(3))) void*)lds, 16, 0, 0);
}

// decode 8 consecutive bf16 (16-byte aligned) to fp32
__device__ __forceinline__ void load8_bf16(const bf16* p, float* f) {
    uint4 raw = *(const uint4*)p;
    unsigned int w0 = raw.x, w1 = raw.y, w2 = raw.z, w3 = raw.w;
    f[0] = __uint_as_float((w0 & 0xffffu) << 16);
    f[1] = __uint_as_float(w0 & 0xffff0000u);
    f[2] = __uint_as_float((w1 & 0xffffu) << 16);
    f[3] = __uint_as_float(w1 & 0xffff0000u);
    f[4] = __uint_as_float((w2 & 0xffffu) << 16);
    f[5] = __uint_as_float(w2 & 0xffff0000u);
    f[6] = __uint_as_float((w3 & 0xffffu) << 16);
    f[7] = __uint_as_float(w3 & 0xffff0000u);
}

// ---------------------------------------------------------------------------
// Input dtype detection (1 = fp32 inputs, 0 = bf16 inputs).
// ---------------------------------------------------------------------------
__global__ void detect_dtype(const void* xsrc, int* flag) {
    const unsigned short* p = (const unsigned short*)xsrc;
    int tid = threadIdx.x;
    int bad = 0;
    for (int i = tid; i < 2048; i += 256) {
        float v = __uint_as_float(((unsigned int)p[i]) << 16);
        if (!isfinite(v) || fabsf(v) > 1e6f) bad = 1;
    }
    __shared__ int sbad;
    if (tid == 0) sbad = 0;
    __syncthreads();
    if (bad) atomicOr(&sbad, 1);
    __syncthreads();
    if (tid == 0) *flag = sbad;
}

__global__ __launch_bounds__(256) void convert_to_bf16(
    const void* __restrict__ src, bf16* __restrict__ dst, int n,
    const int* __restrict__ flag)
{
    int i = blockIdx.x * 256 + threadIdx.x;
    if (i >= n) return;
    if (*flag)
        dst[i] = f2bf(((const float*)src)[i]);
    else
        dst[i] = ((const bf16*)src)[i];
}

// batch of small conversions in a single dispatch (saves ~7 launches)
struct CvtBatch {
    const void* src[8];
    bf16* dst[8];
    int n[8];
    int blockStart[9];   // prefix of ceil(n/256)
    int count;
};
__global__ __launch_bounds__(256) void convert_batch(CvtBatch b, const int* __restrict__ flag) {
    int bi = blockIdx.x;
    int seg = 0;
    while (seg + 1 < b.count && bi >= b.blockStart[seg + 1]) seg++;
    int i = (bi - b.blockStart[seg]) * 256 + threadIdx.x;
    if (i >= b.n[seg]) return;
    if (*flag)
        b.dst[seg][i] = f2bf(((const float*)b.src[seg])[i]);
    else
        b.dst[seg][i] = ((const bf16*)b.src[seg])[i];
}

// combine 4 split-K fp32 partials -> bf16 (coalesced: 1 elem/thread)
__global__ __launch_bounds__(256) void combine_splitk(
    const float* __restrict__ p, bf16* __restrict__ out, int n, int stride)
{
    int i = blockIdx.x * 256 + threadIdx.x;
    if (i >= n) return;
    float v = (p[i] + p[i + (size_t)stride]) +
              (p[i + 2 * (size_t)stride] + p[i + 3 * (size_t)stride]);
    out[i] = f2bf(v);
}

// ---------------------------------------------------------------------------
// Legacy 128x128 async-staged MFMA GEMM (m97 structure).
// EPI: 0 plain, 1 softplus+bias, 2 split store, 3 split-K fp32 partials
// (EPI=3: blockIdx.x = K-slice; partials at (float*)C + (slice*Mrows+row)*ldc.)
// ---------------------------------------------------------------------------
template <int EPI>
__global__ __launch_bounds__(256) void gemm_async(
    const bf16* __restrict__ A, int lda,
    const bf16* __restrict__ W, int ldw, int K,
    const bf16* __restrict__ bias,
    bf16* __restrict__ C, bf16* __restrict__ C2, int ldc,
    int N, int Nsplit)
{
    __shared__ short As[128 * 32];   // [m][k], 8 KB
    __shared__ short Bs[128 * 32];   // [n][k], 8 KB

    const int tid = threadIdx.x;
    const int m0 = blockIdx.y * 128;
    const int n0 = (EPI == 3) ? 0 : blockIdx.x * 128;
    const int ks = (EPI == 3) ? (int)blockIdx.x * K : 0;   // K-slice offset
    const int wid = tid >> 6;
    const int lane = tid & 63;
    const int wm = wid & 1;
    const int wn = wid >> 1;
    const int lm = lane & 15;
    const int quad = lane >> 4;

    floatx4 acc[4][4];
#pragma unroll
    for (int i = 0; i < 4; i++)
#pragma unroll
        for (int j = 0; j < 4; j++) acc[i][j] = (floatx4){0.f, 0.f, 0.f, 0.f};

    for (int k0 = 0; k0 < K; k0 += 32) {
#pragma unroll
        for (int j = 0; j < 2; j++) {
            int cbase = (wid * 2 + j) * 64;       // wave-uniform
            int c = cbase + lane;
            int row = c >> 2, seg = c & 3;
            gl2lds16(A + (size_t)(m0 + row) * lda + ks + k0 + seg * 8, &As[cbase * 8]);
        }
#pragma unroll
        for (int j = 0; j < 2; j++) {
            int cbase = (wid * 2 + j) * 64;
            int c = cbase + lane;
            int row = c >> 2, seg = c & 3;
            int wrow = n0 + row; if (wrow >= N) wrow = N - 1;
            gl2lds16(W + (size_t)wrow * ldw + ks + k0 + seg * 8, &Bs[cbase * 8]);
        }
        __syncthreads();

        short8 af[4], bfr[4];
#pragma unroll
        for (int mt = 0; mt < 4; mt++)
            af[mt] = *(const short8*)&As[(wm * 64 + mt * 16 + lm) * 32 + quad * 8];
#pragma unroll
        for (int nt = 0; nt < 4; nt++)
            bfr[nt] = *(const short8*)&Bs[(wn * 64 + nt * 16 + lm) * 32 + quad * 8];
        __syncthreads();

#pragma unroll
        for (int mt = 0; mt < 4; mt++)
#pragma unroll
            for (int nt = 0; nt < 4; nt++)
                acc[mt][nt] = __builtin_amdgcn_mfma_f32_16x16x32_bf16(
                    af[mt], bfr[nt], acc[mt][nt], 0, 0, 0);
    }

#pragma unroll
    for (int mt = 0; mt < 4; mt++) {
#pragma unroll
        for (int nt = 0; nt < 4; nt++) {
            int col = n0 + wn * 64 + nt * 16 + lm;
            if (col >= N) continue;
            int rbase = m0 + wm * 64 + mt * 16 + quad * 4;
#pragma unroll
            for (int r = 0; r < 4; r++) {
                float v = acc[mt][nt][r];
                if (EPI == 3) {
                    ((float*)C)[((size_t)blockIdx.x * Nsplit + rbase + r) * ldc + col] = v;
                } else if (EPI == 1) {
                    C[(size_t)(rbase + r) * ldc + col] = f2bf(softplus_f(v + bf2f(bias[col])));
                } else if (EPI == 2) {
                    if (col < Nsplit)
                        C[(size_t)(rbase + r) * ldc + col] = f2bf(v);
                    else
                        C2[(size_t)(rbase + r) * ldc + (col - Nsplit)] = f2bf(v);
                } else {
                    C[(size_t)(rbase + r) * ldc + col] = f2bf(v);
                }
            }
        }
    }
}

// ---------------------------------------------------------------------------
// 256x256 MFMA GEMM.  R10 rotate-prefetch schedule (proven).
// C[M,N] = A[M,K] @ W[N,K]^T.  M%256==0, N%256==0, K%64==0, K>=64.
// EPI: 0 plain, 1 softplus+bias, 2 split.  R7 XCD swizzle (proven).
// ---------------------------------------------------------------------------
template <int EPI>
__global__ __launch_bounds__(512, 2) void gemm256(
    const bf16* __restrict__ A, int lda,
    const bf16* __restrict__ W, int ldw, int K,
    const bf16* __restrict__ bias,
    bf16* __restrict__ C, bf16* __restrict__ C2, int ldc,
    int NBX, int Nsplit)
{
    __shared__ short lds[65536];   // 128 KB: [buf][A 16384 | B 16384] shorts

    const int tid = threadIdx.x;
    const int wid = tid >> 6;
    const int lane = tid & 63;
    const int lm = lane & 15;
    const int quad = lane >> 4;
    const int wm = wid >> 2;      // 0..1
    const int wn = wid & 3;       // 0..3

    // XCD-aware bijective swizzle (caller guarantees nwg % 8 == 0) — R7 form
    const int nwg = (int)gridDim.x;
    const int wg = (int)blockIdx.x;
    const int swz = (wg & 7) * (nwg >> 3) + (wg >> 3);
    const int by = swz / NBX;
    const int bx = swz - by * NBX;
    const int m0 = by * 256;
    const int n0 = bx * 256;

    const int NT = K >> 6;

    floatx4 acc[2][4][2][2];
#pragma unroll
    for (int a = 0; a < 2; a++)
#pragma unroll
        for (int b = 0; b < 4; b++)
#pragma unroll
            for (int c = 0; c < 2; c++)
#pragma unroll
                for (int d = 0; d < 2; d++) acc[a][b][c][d] = (floatx4){0.f, 0.f, 0.f, 0.f};

    // stage one 16 KB half of the A (resp. B) tile of K-step t_ into buffer bsel.
    auto stageA = [&](int bsel, int t_, int half) {
        short* base = &lds[bsel * 32768];
        const bf16* g = A + (size_t)m0 * lda + t_ * 64;
#pragma unroll
        for (int part = 0; part < 2; part++) {
            int cbase = half * 512 + part * 1024 + wid * 64;   // wave-uniform
            int c = cbase + lane;
            int row = c >> 3;
            int gs = (c & 7) ^ (row & 7);                      // inverse swizzle on source
            gl2lds16(g + (size_t)row * lda + gs * 8, base + cbase * 8);
        }
    };
    auto stageB = [&](int bsel, int t_, int half) {
        short* base = &lds[bsel * 32768 + 16384];
        const bf16* g = W + (size_t)n0 * ldw + t_ * 64;
#pragma unroll
        for (int part = 0; part < 2; part++) {
            int cbase = half * 1024 + part * 512 + wid * 64;
            int c = cbase + lane;
            int row = c >> 3;
            int gs = (c & 7) ^ (row & 7);
            gl2lds16(g + (size_t)row * ldw + gs * 8, base + cbase * 8);
        }
    };

    // ---- prologue
    stageA(0, 0, 0); stageA(0, 0, 1); stageB(0, 0, 0); stageB(0, 0, 1);
    if (NT > 1) { stageA(1, 1, 0); stageB(1, 1, 1); }
    if (NT > 1) asm volatile("s_waitcnt vmcnt(4)" ::: "memory");
    else        asm volatile("s_waitcnt vmcnt(0)" ::: "memory");
    __builtin_amdgcn_s_barrier();

#define READ_A(BASE, DST, MH)                                                   \
    _Pragma("unroll")                                                           \
    for (int mt = 0; mt < 4; mt++) {                                            \
        int r = wm * 128 + (MH) * 64 + mt * 16 + lm;                            \
        _Pragma("unroll")                                                       \
        for (int kk = 0; kk < 2; kk++)                                          \
            DST[mt][kk] = *(const short8*)&(BASE)[r * 64 + (((kk * 4 + quad) ^ (r & 7)) * 8)]; \
    }
#define READ_B(BASE, DST, NH)                                                   \
    _Pragma("unroll")                                                           \
    for (int nf = 0; nf < 2; nf++) {                                            \
        int r = (NH) * 128 + wn * 32 + nf * 16 + lm;                            \
        _Pragma("unroll")                                                       \
        for (int kk = 0; kk < 2; kk++)                                          \
            DST[nf][kk] = *(const short8*)&(BASE)[r * 64 + (((kk * 4 + quad) ^ (r & 7)) * 8)]; \
    }
#define MFMA16(AF, BV, MH, NH)                                                  \
    __builtin_amdgcn_s_setprio(1);                                              \
    _Pragma("unroll")                                                           \
    for (int mt = 0; mt < 4; mt++)                                              \
        _Pragma("unroll")                                                       \
        for (int nf = 0; nf < 2; nf++)                                          \
            _Pragma("unroll")                                                   \
            for (int kk = 0; kk < 2; kk++)                                      \
                acc[MH][mt][NH][nf] = __builtin_amdgcn_mfma_f32_16x16x32_bf16(  \
                    AF[mt][kk], BV[nf][kk], acc[MH][mt][NH][nf], 0, 0, 0);      \
    __builtin_amdgcn_s_setprio(0);

    short8 af0[4][2], af1[4][2], bv0[2][2], bv1[2][2];
    // prologue prefetch: tile0 af0/bv0
    {
        short* An_ = &lds[0];
        short* Bn_ = &lds[16384];
        READ_A(An_, af0, 0)
        READ_B(Bn_, bv0, 0)
    }

    for (int t = 0; t < NT; t++) {
        const int buf = t & 1;
        const int bufn = buf ^ 1;
        short* As_ = &lds[buf * 32768];
        short* Bs_ = &lds[buf * 32768 + 16384];

        READ_B(Bs_, bv1, 1)
        READ_A(As_, af1, 1)

        if (t + 1 < NT) { stageA(bufn, t + 1, 1); stageB(bufn, t + 1, 0); }

        MFMA16(af0, bv0, 0, 0)      // C0 — waits only on prefetched af0/bv0
        MFMA16(af0, bv1, 0, 1)      // C1 — bv1 drained under C0

        __builtin_amdgcn_s_barrier();   // #1: af0-region & bv1-region consumed

        if (t + 2 < NT) { stageA(buf, t + 2, 0); stageB(buf, t + 2, 1); }

        MFMA16(af1, bv0, 1, 0)      // C3 — af0/bv0 registers now dead

        if (t + 2 < NT)      { asm volatile("s_waitcnt vmcnt(4)" ::: "memory"); }
        else if (t + 1 < NT) { asm volatile("s_waitcnt vmcnt(0)" ::: "memory"); }
        asm volatile("s_waitcnt lgkmcnt(0)" ::: "memory");   // pin tile-t reads
        __builtin_amdgcn_s_barrier();   // #2: buf(t+1) proven complete

        if (t + 1 < NT) {
            short* An_ = &lds[bufn * 32768];
            short* Bn_ = &lds[bufn * 32768 + 16384];
            READ_A(An_, af0, 0)     // prefetch tile t+1 into rotated regs
            READ_B(Bn_, bv0, 0)
        }

        MFMA16(af1, bv1, 1, 1)      // C2 — regs only; prefetch drains under it
    }
#undef READ_A
#undef READ_B
#undef MFMA16

    // epilogue: C/D layout col = lane&15, row = quad*4 + r  [m89/m91]
#pragma unroll
    for (int mh = 0; mh < 2; mh++)
#pragma unroll
        for (int mt = 0; mt < 4; mt++)
#pragma unroll
            for (int nh = 0; nh < 2; nh++)
#pragma unroll
                for (int nf = 0; nf < 2; nf++) {
                    int col = n0 + nh * 128 + wn * 32 + nf * 16 + lm;
                    int rbase = m0 + wm * 128 + mh * 64 + mt * 16 + quad * 4;
#pragma unroll
                    for (int r = 0; r < 4; r++) {
                        float v = acc[mh][mt][nh][nf][r];
                        if (EPI == 1) v = softplus_f(v + bf2f(bias[col]));
                        if (EPI == 2) {
                            if (col < Nsplit)
                                C[(size_t)(rbase + r) * ldc + col] = f2bf(v);
                            else
                                C2[(size_t)(rbase + r) * ldc + (col - Nsplit)] = f2bf(v);
                        } else {
                            C[(size_t)(rbase + r) * ldc + col] = f2bf(v);
                        }
                    }
                }
}

// ---------------------------------------------------------------------------
// Causal depthwise conv1d (width 4) + bias + SiLU.  R10: x8 vectorized
// (short8 loads/stores, 8 channels/thread — G13).
// ---------------------------------------------------------------------------
__global__ __launch_bounds__(256) void conv_silu(
    const bf16* __restrict__ u,
    bf16* __restrict__ u_c,
    const bf16* __restrict__ w,
    const bf16* __restrict__ bias)
{
    int gid = blockIdx.x * 256 + threadIdx.x;
    if (gid >= NROWS * (D_INNER / 8)) return;
    int dg = gid & (D_INNER / 8 - 1);
    int row = gid >> 8;
    int l = row & (LL - 1);
    int d0 = dg * 8;

    float wv[32];   // taps for 8 channels: wv[j*4+t]
    load8_bf16(w + d0 * 4, wv);
    load8_bf16(w + d0 * 4 + 8, wv + 8);
    load8_bf16(w + d0 * 4 + 16, wv + 16);
    load8_bf16(w + d0 * 4 + 24, wv + 24);
    float acc[8];
    load8_bf16(bias + d0, acc);

#pragma unroll
    for (int t = 0; t < 4; t++) {
        int ls = l - 3 + t;
        if (ls >= 0) {
            float uv[8];
            load8_bf16(u + (size_t)(row - 3 + t) * D_INNER + d0, uv);
#pragma unroll
            for (int j = 0; j < 8; j++)
                acc[j] = fmaf(wv[j * 4 + t], uv[j], acc[j]);
        }
    }

    union { short8 v; unsigned short s[8]; } o;
#pragma unroll
    for (int j = 0; j < 8; j++)
        o.s[j] = __bfloat16_as_ushort(f2bf(silu_f(acc[j])));
    *(short8*)&u_c[(size_t)row * D_INNER + d0] = o.v;
}

// ---------------------------------------------------------------------------
// Chunked selective scan (3 phases).  R6: A_log read in original precision
// so the POW16 structure check passes (bf16 copy failed the 1e-4 check).
// ---------------------------------------------------------------------------

// dA[0..15] = q^(n+1), 15 muls, depth ~4
#define POW16(DA, Q) do {                                                     \
    float q1 = (Q);                                                           \
    float q2 = q1 * q1;                                                       \
    float q3 = q2 * q1;                                                       \
    float q4 = q2 * q2;                                                       \
    float q8 = q4 * q4;                                                       \
    DA[0] = q1;       DA[1] = q2;       DA[2] = q3;       DA[3] = q4;         \
    DA[4] = q4 * q1;  DA[5] = q4 * q2;  DA[6] = q4 * q3;  DA[7] = q8;         \
    DA[8] = q8 * q1;  DA[9] = q8 * q2;  DA[10] = q8 * q3; DA[11] = q8 * q4;   \
    DA[12] = q8 * DA[4]; DA[13] = q8 * DA[5]; DA[14] = q8 * DA[6];            \
    DA[15] = q8 * q8;                                                         \
} while (0)

__device__ __forceinline__ bool ac_structured(const float* Ac) {
    float a0 = Ac[0];
    bool ok = true;
#pragma unroll
    for (int n = 1; n < 16; n++) {
        float want = (float)(n + 1) * a0;
        ok = ok && (fabsf(Ac[n] - want) <= 1e-4f * fabsf(want) + 1e-12f);
    }
    return ok;
}

// load A_log row d (16 values) in original precision, produce exp2-domain Ac
__device__ __forceinline__ void load_Ac(const void* A_log_raw, int fp32, int d, float* Ac) {
    float f[16];
    if (fp32) {
        const float* ap = (const float*)A_log_raw + (size_t)d * 16;
#pragma unroll
        for (int n = 0; n < 16; n++) f[n] = ap[n];
    } else {
        const bf16* ap = (const bf16*)A_log_raw + (size_t)d * 16;
        load8_bf16(ap, f);
        load8_bf16(ap + 8, f + 8);
    }
#pragma unroll
    for (int n = 0; n < 16; n++) Ac[n] = -__expf(f[n]) * 1.4426950408889634f;
}

__global__ __launch_bounds__(256) void scan_p1(
    const bf16* __restrict__ delta,
    const bf16* __restrict__ uc,
    const bf16* __restrict__ x_dbl,
    const void* __restrict__ A_log_raw,
    const int* __restrict__ flag,
    float* __restrict__ Pbuf, float* __restrict__ Sbuf)
{
    __shared__ float Bsh[TCHUNK * 16];
    const int tid = threadIdx.x;
    const int bx = blockIdx.x;
    const int dt = bx & 7;
    const int c = (bx >> 3) & (NCHUNK - 1);
    const int b = bx / (NCHUNK * 8);
    const int d = dt * 256 + tid;
    const int rowb = b * LL + c * TCHUNK;

    if (tid < TCHUNK) {
        float f[16];
        const bf16* p = x_dbl + (size_t)(rowb + tid) * 96 + DT_RANK;
        load8_bf16(p, f);
        load8_bf16(p + 8, f + 8);
#pragma unroll
        for (int n = 0; n < 16; n++) Bsh[tid * 16 + n] = f[n];
    }

    float Ac[16];   // -exp(A_log) * log2e  (exp2-domain)
    load_Ac(A_log_raw, *flag, d, Ac);
    const float a0 = Ac[0];
    const bool fast = ac_structured(Ac);
    __syncthreads();

    float h[16];
    float sdl = 0.f;   // sum of dl over chunk -> Pp via exp2(Ac*sdl)
#pragma unroll
    for (int n = 0; n < 16; n++) h[n] = 0.f;

    size_t g = (size_t)rowb * 2048 + d;
    float dl = bf2f(delta[g]);
    float uv = bf2f(uc[g]);

#define P1_BODY(DA_STMT)                                                      \
    for (int t = 0; t < TCHUNK; t++) {                                        \
        float dl_n = 0.f, uv_n = 0.f;                                         \
        if (t + 1 < TCHUNK) {                                                 \
            g += 2048;                                                        \
            dl_n = bf2f(delta[g]);                                            \
            uv_n = bf2f(uc[g]);                                               \
        }                                                                     \
        float dlu = dl * uv;                                                  \
        float dAv[16];                                                        \
        DA_STMT;                                                              \
        float bb[16];                                                         \
        {                                                                     \
            const float4* Bv = (const float4*)&Bsh[t * 16];                   \
            *(float4*)&bb[0] = Bv[0]; *(float4*)&bb[4] = Bv[1];               \
            *(float4*)&bb[8] = Bv[2]; *(float4*)&bb[12] = Bv[3];              \
        }                                                                     \
        _Pragma("unroll")                                                     \
        for (int n = 0; n < 16; n++)                                          \
            h[n] = fmaf(dAv[n], h[n], dlu * bb[n]);                           \
        sdl += dl;                                                            \
        dl = dl_n; uv = uv_n;                                                 \
    }

    if (fast) {
        P1_BODY(POW16(dAv, exp2_raw(dl * a0)))
    } else {
        P1_BODY({ _Pragma("unroll") for (int n = 0; n < 16; n++) dAv[n] = exp2_raw(dl * Ac[n]); })
    }
#undef P1_BODY

    size_t base = (((size_t)b * NCHUNK + c) * 16) * 2048 + d;
#pragma unroll
    for (int n = 0; n < 16; n++) {
        Pbuf[base + (size_t)n * 2048] = exp2_raw(Ac[n] * sdl);
        Sbuf[base + (size_t)n * 2048] = h[n];
    }
}

__global__ __launch_bounds__(256) void scan_p2(
    float* __restrict__ Pbuf, const float* __restrict__ Sbuf)
{
    int gid = blockIdx.x * 256 + threadIdx.x;
    int b = gid >> 15;
    int n = (gid >> 11) & 15;
    int d = gid & 2047;
    float hinit = 0.f;
    for (int c = 0; c < NCHUNK; c++) {
        size_t idx = (((size_t)b * NCHUNK + c) * 16 + n) * 2048 + d;
        float p = Pbuf[idx];
        float s = Sbuf[idx];
        Pbuf[idx] = hinit;
        hinit = fmaf(p, hinit, s);
    }
}

__global__ __launch_bounds__(256) void scan_p3(
    const bf16* __restrict__ delta,
    const bf16* uc,
    const bf16* __restrict__ x_dbl,
    const bf16* __restrict__ z,
    const void* __restrict__ A_log_raw,
    const int* __restrict__ flag,
    const bf16* __restrict__ Dvec,
    const float* __restrict__ Hinit,
    bf16* yg)
{
    __shared__ float Bsh[TCHUNK * 16];
    __shared__ float Csh[TCHUNK * 16];
    const int tid = threadIdx.x;
    const int bx = blockIdx.x;
    const int dt = bx & 7;
    const int c = (bx >> 3) & (NCHUNK - 1);
    const int b = bx / (NCHUNK * 8);
    const int d = dt * 256 + tid;
    const int rowb = b * LL + c * TCHUNK;

    if (tid < TCHUNK) {
        float f[16];
        const bf16* p = x_dbl + (size_t)(rowb + tid) * 96 + DT_RANK;
        load8_bf16(p, f);
        load8_bf16(p + 8, f + 8);
#pragma unroll
        for (int n = 0; n < 16; n++) Bsh[tid * 16 + n] = f[n];
        load8_bf16(p + 16, f);
        load8_bf16(p + 24, f + 8);
#pragma unroll
        for (int n = 0; n < 16; n++) Csh[tid * 16 + n] = f[n];
    }

    float Ac[16];   // -exp(A_log) * log2e  (exp2-domain)
    load_Ac(A_log_raw, *flag, d, Ac);
    const float a0 = Ac[0];
    const bool fast = ac_structured(Ac);
    const float Dv = bf2f(Dvec[d]);
    __syncthreads();

    float h[16];
    size_t base = (((size_t)b * NCHUNK + c) * 16) * 2048 + d;
#pragma unroll
    for (int n = 0; n < 16; n++) h[n] = Hinit[base + (size_t)n * 2048];

    size_t g = (size_t)rowb * 2048 + d;
    float dl = bf2f(delta[g]);
    float uv = bf2f(uc[g]);
    float zv = bf2f(z[g]);
    size_t gw = g;

#define P3_BODY(DA_STMT)                                                      \
    for (int t = 0; t < TCHUNK; t++) {                                        \
        float dl_n = 0.f, uv_n = 0.f, zv_n = 0.f;                             \
        if (t + 1 < TCHUNK) {                                                 \
            g += 2048;                                                        \
            dl_n = bf2f(delta[g]);                                            \
            uv_n = bf2f(uc[g]);                                               \
            zv_n = bf2f(z[g]);                                                \
        }                                                                     \
        float dlu = dl * uv;                                                  \
        float dAv[16];                                                        \
        DA_STMT;                                                              \
        float bb[16], cc[16];                                                 \
        {                                                                     \
            const float4* Bv = (const float4*)&Bsh[t * 16];                   \
            const float4* Cv = (const float4*)&Csh[t * 16];                   \
            *(float4*)&bb[0] = Bv[0]; *(float4*)&bb[4] = Bv[1];               \
            *(float4*)&bb[8] = Bv[2]; *(float4*)&bb[12] = Bv[3];              \
            *(float4*)&cc[0] = Cv[0]; *(float4*)&cc[4] = Cv[1];               \
            *(float4*)&cc[8] = Cv[2]; *(float4*)&cc[12] = Cv[3];              \
        }                                                                     \
        float yp0 = 0.f, yp1 = 0.f, yp2 = 0.f, yp3 = 0.f;                     \
        _Pragma("unroll")                                                     \
        for (int n = 0; n < 16; n += 4) {                                     \
            h[n]     = fmaf(dAv[n],     h[n],     dlu * bb[n]);               \
            h[n + 1] = fmaf(dAv[n + 1], h[n + 1], dlu * bb[n + 1]);           \
            h[n + 2] = fmaf(dAv[n + 2], h[n + 2], dlu * bb[n + 2]);           \
            h[n + 3] = fmaf(dAv[n + 3], h[n + 3], dlu * bb[n + 3]);           \
            yp0 = fmaf(h[n],     cc[n],     yp0);                             \
            yp1 = fmaf(h[n + 1], cc[n + 1], yp1);                             \
            yp2 = fmaf(h[n + 2], cc[n + 2], yp2);                             \
            yp3 = fmaf(h[n + 3], cc[n + 3], yp3);                             \
        }                                                                     \
        float y = (yp0 + yp1) + (yp2 + yp3);                                  \
        y = fmaf(uv, Dv, y);                                                  \
        yg[gw] = f2bf(y * silu_f(zv));                                        \
        gw += 2048;                                                           \
        dl = dl_n; uv = uv_n; zv = zv_n;                                      \
    }

    if (fast) {
        P3_BODY(POW16(dAv, exp2_raw(dl * a0)))
    } else {
        P3_BODY({ _Pragma("unroll") for (int n = 0; n < 16; n++) dAv[n] = exp2_raw(dl * Ac[n]); })
    }
#undef P3_BODY
}

// ---------------------------------------------------------------------------
// LayerNorm over last dim (1024). Output dtype per flag (1=fp32, 0=bf16).
// ---------------------------------------------------------------------------
__global__ __launch_bounds__(256) void out_ln(
    const bf16* __restrict__ o,
    const bf16* __restrict__ lw,
    const bf16* __restrict__ lb,
    void* __restrict__ outv,
    const int* __restrict__ flag)
{
    __shared__ float sm[4];
    const int row = blockIdx.x;
    const int tid = threadIdx.x;
    const int lane = tid & 63;
    const int wid = tid >> 6;
    const int c = tid * 4;

    const bf16* rp = o + (size_t)row * 1024 + c;
    float v0 = bf2f(rp[0]), v1 = bf2f(rp[1]), v2 = bf2f(rp[2]), v3 = bf2f(rp[3]);

    float s = v0 + v1 + v2 + v3;
#pragma unroll
    for (int off = 1; off < 64; off <<= 1) s += __shfl_xor(s, off, 64);
    if (lane == 0) sm[wid] = s;
    __syncthreads();
    float mu = (sm[0] + sm[1] + sm[2] + sm[3]) * (1.f / 1024.f);
    __syncthreads();

    float dx0 = v0 - mu, dx1 = v1 - mu, dx2 = v2 - mu, dx3 = v3 - mu;
    float q = dx0 * dx0 + dx1 * dx1 + dx2 * dx2 + dx3 * dx3;
#pragma unroll
    for (int off = 1; off < 64; off <<= 1) q += __shfl_xor(q, off, 64);
    if (lane == 0) sm[wid] = q;
    __syncthreads();
    float var = (sm[0] + sm[1] + sm[2] + sm[3]) * (1.f / 1024.f);
    float inv = rsqrtf(var + 1e-5f);

    float w0 = bf2f(lw[c]), w1 = bf2f(lw[c + 1]), w2 = bf2f(lw[c + 2]), w3 = bf2f(lw[c + 3]);
    float b0 = bf2f(lb[c]), b1 = bf2f(lb[c + 1]), b2 = bf2f(lb[c + 2]), b3 = bf2f(lb[c + 3]);
    float r0 = dx0 * inv * w0 + b0;
    float r1 = dx1 * inv * w1 + b1;
    float r2 = dx2 * inv * w2 + b2;
    float r3 = dx3 * inv * w3 + b3;

    if (*flag) {
        float4* wp = (float4*)((float*)outv + (size_t)row * 1024 + c);
        *wp = make_float4(r0, r1, r2, r3);
    } else {
        bf16* wp = (bf16*)outv + (size_t)row * 1024 + c;
        wp[0] = f2bf(r0); wp[1] = f2bf(r1); wp[2] = f2bf(r2); wp[3] = f2bf(r3);
    }
}

// ---------------------------------------------------------------------------
extern "C" void kernel_launch(void* const* d_in, const int* in_sizes, int n_in,
                              void* d_out, int out_size, void* d_ws, size_t ws_size,
                              hipStream_t stream)
{
    const void* x          = d_in[0];
    const void* in_proj_w  = d_in[1];
    const void* conv_w     = d_in[2];
    const void* conv_b     = d_in[3];
    const void* x_proj_w   = d_in[4];
    const void* dt_proj_w  = d_in[5];
    const void* dt_proj_b  = d_in[6];
    const void* A_log      = d_in[7];
    const void* Dvec       = d_in[8];
    const void* out_proj_w = d_in[9];
    const void* ln_w       = d_in[10];
    const void* ln_b       = d_in[11];

    size_t nBig = (size_t)NROWS * D_INNER;
    size_t xdblN = (size_t)NROWS * 96;
    size_t need = (3 * nBig + xdblN + 196608) * 2;
    if (ws_size < need) {
        hipMemsetAsync(d_out, 0, (size_t)out_size * 2, stream);
        return;
    }

    bf16* bufA = (bf16*)d_ws;       // u -> x_proj_w copy -> delta -> out_proj_w copy
    bf16* bufZ = bufA + nBig;       // z -> y_out
    bf16* bufC = bufZ + nBig;       // x+in_proj_w copies -> u_c / y_gated
    bf16* bufX = bufC + nBig;       // x_dbl
    bf16* bufS = bufX + xdblN;      // flag + small consts

    int*  flag    = (int*)bufS;
    bf16* c_convw = bufS + 16;
    bf16* c_convb = c_convw + 8192;
    bf16* c_dtw   = c_convb + 2048;
    bf16* c_dtb   = c_dtw + 131072;
    bf16* c_Alog  = c_dtb + 2048;
    bf16* c_D     = c_Alog + 32768;
    bf16* c_lnw   = c_D + 2048;
    bf16* c_lnb   = c_lnw + 1024;

    bf16* c_x    = bufC;
    bf16* c_wip  = bufC + (size_t)NROWS * 1024;
    bf16* c_xpw  = bufA;
    bf16* c_opw  = bufA;
    bf16* u      = bufA;
    bf16* delta  = bufA;
    bf16* zbuf   = bufZ;
    bf16* y_out  = bufZ;
    bf16* u_c    = bufC;
    bf16* x_dbl  = bufX;

    // d_out scratch timeline: [x_proj split-K partials 25.2MB] -> [scan P/S
    // 33.5MB] -> [LN output].  No temporal overlap.
    float* Ptmp = (float*)d_out;                      // 4 x 16384 x 96 fp32
    float* Pbuf = (float*)d_out;
    float* Sbuf = Pbuf + (size_t)BB * NCHUNK * 16 * 2048;

    dim3 blk(256);
    auto cvt = [&](const void* src, bf16* dst, int n) {
        convert_to_bf16<<<dim3((n + 255) / 256), blk, 0, stream>>>(src, dst, n, flag);
    };

    // 0. detect input dtype
    detect_dtype<<<dim3(1), blk, 0, stream>>>(x, flag);

    // small consts: one batched dispatch
    {
        CvtBatch b{};
        const void* srcs[8] = {conv_w, conv_b, dt_proj_w, dt_proj_b, A_log, Dvec, ln_w, ln_b};
        bf16* dsts[8] = {c_convw, c_convb, c_dtw, c_dtb, c_Alog, c_D, c_lnw, c_lnb};
        int ns[8] = {D_INNER * 4, D_INNER, D_INNER * DT_RANK, D_INNER,
                     D_INNER * D_STATE, D_INNER, D_MODEL, D_MODEL};
        int acc = 0;
        for (int i = 0; i < 8; i++) {
            b.src[i] = srcs[i]; b.dst[i] = dsts[i]; b.n[i] = ns[i];
            b.blockStart[i] = acc; acc += (ns[i] + 255) / 256;
        }
        b.blockStart[8] = acc; b.count = 8;
        convert_batch<<<dim3(acc), blk, 0, stream>>>(b, flag);
    }

    cvt(x, c_x, NROWS * D_MODEL);
    cvt(in_proj_w, c_wip, 2 * D_INNER * D_MODEL);

    // 1. in_proj: 256x256 kernel, N=4096, split store u | z
    gemm256<2><<<dim3(16 * 64), dim3(512), 0, stream>>>(
        c_x, D_MODEL, c_wip, D_MODEL, D_MODEL, nullptr,
        u, zbuf, D_INNER, /*NBX=*/16, /*Nsplit=*/D_INNER);

    // 2. conv + SiLU -> u_c (x8 vectorized)
    conv_silu<<<dim3(NROWS * (D_INNER / 8) / 256), blk, 0, stream>>>(u, u_c, c_convw, c_convb);

    // 3. x_proj (N=96): split-K x4 — grid (4,128) = 512 blocks (full chip)
    cvt(x_proj_w, c_xpw, 96 * D_INNER);
    gemm_async<3><<<dim3(4, NROWS / 128), blk, 0, stream>>>(
        u_c, D_INNER, c_xpw, D_INNER, D_INNER / 4, nullptr,
        (bf16*)Ptmp, nullptr, 96, 96, /*Mrows=*/NROWS);
    combine_splitk<<<dim3((NROWS * 96 + 255) / 256), blk, 0, stream>>>(
        Ptmp, x_dbl, NROWS * 96, NROWS * 96);

    // 4. dt_proj + softplus -> delta: 256² kernel, NT=1, fast-softplus epilogue
    gemm256<1><<<dim3(8 * 64), dim3(512), 0, stream>>>(
        x_dbl, 96, c_dtw, DT_RANK, DT_RANK, c_dtb,
        delta, nullptr, D_INNER, /*NBX=*/8, /*Nsplit=*/0);

    // 5. chunked selective scan (3 phases), gate fused; in-place into u_c
    scan_p1<<<dim3(BB * NCHUNK * 8), blk, 0, stream>>>(
        delta, u_c, x_dbl, A_log, flag, Pbuf, Sbuf);
    scan_p2<<<dim3(BB * 16 * 2048 / 256), blk, 0, stream>>>(Pbuf, Sbuf);
    scan_p3<<<dim3(BB * NCHUNK * 8), blk, 0, stream>>>(
        delta, u_c, x_dbl, zbuf, A_log, flag, c_D, Pbuf, u_c);

    // 6. out_proj -> y_out in bufZ: 256x256 kernel
    cvt(out_proj_w, c_opw, D_MODEL * D_INNER);
    gemm256<0><<<dim3(4 * 64), dim3(512), 0, stream>>>(
        u_c, D_INNER, c_opw, D_INNER, D_INNER, nullptr,
        y_out, nullptr, D_MODEL, /*NBX=*/4, /*Nsplit=*/0);

    // 7. LayerNorm -> d_out
    out_ln<<<dim3(NROWS), blk, 0, stream>>>(y_out, c_lnw, c_lnb, d_out, flag);
}